// Round 1
// baseline (12089.082 us; speedup 1.0000x reference)
//
#include <hip/hip_runtime.h>

// Seq2seq LSTM (B=64, T=256, E=512, H=1024, V_TGT=64) on gfx950.
// Plan:
//   k1a: gather+convert A_bf16[16512][512] (rows 0..16384 = emb_src[src tok],
//        rows 16384..16448 = emb_tgt (decoder x-table), rest zero)
//   k1w: W_lstm fp32 [1536][4096] -> WpermT bf16 [4096][1536] (transposed,
//        columns permuted so WG w's 16 gate columns are contiguous:
//        n = w*16 + u*4 + g  <->  orig col g*1024 + 4w + u)
//   k1p: W_proj [1024][64] -> WprojT bf16 [64][1024]
//   k2 : Zx bf16 [16512][4096] = A @ Wx  (MFMA 16x16x32, 128x128 tile)
//   k3 : persistent 256-WG recurrent kernel, 512 steps, custom grid barrier,
//        c-state in registers, W_h slice in LDS, double-buffered h
//   k4 : projection + softmax -> d_out fp32 [64][256][64]

typedef __attribute__((ext_vector_type(8))) short short8;        // bf16 frag
typedef __attribute__((ext_vector_type(4))) float f32x4;         // MFMA acc
typedef __attribute__((ext_vector_type(4))) float float4v;
typedef __attribute__((ext_vector_type(4))) unsigned short ushort4v;

#define MFMA16(A, B, C) __builtin_amdgcn_mfma_f32_16x16x32_bf16((A), (B), (C), 0, 0, 0)

__device__ __forceinline__ unsigned short f2bf(float f) {
  union { float f; unsigned u; } v; v.f = f;
  unsigned r = (v.u + 0x7fffu + ((v.u >> 16) & 1u)) >> 16;   // RNE, no NaN in data
  return (unsigned short)r;
}
__device__ __forceinline__ float bf2f(unsigned short h) {
  union { unsigned u; float f; } v; v.u = ((unsigned)h) << 16;
  return v.f;
}
__device__ __forceinline__ float sigf(float x) { return 1.0f / (1.0f + __expf(-x)); }
// tanh = 1 - 2/(e^{2x}+1); saturates cleanly at +-1 for large |x|, no NaN.
__device__ __forceinline__ float tanhf_fast(float x) { return 1.0f - 2.0f / (1.0f + __expf(2.0f * x)); }

// ---------------------------------------------------------------- k1a
__global__ __launch_bounds__(128)
void k1a_gather(const int* __restrict__ tok_src,
                const float* __restrict__ emb_src,
                const float* __restrict__ emb_tgt,
                unsigned short* __restrict__ A)
{
  const int n = blockIdx.x;     // 0..16511
  const int i = threadIdx.x;    // 0..127, each does 4 elements
  float4v v = {0.f, 0.f, 0.f, 0.f};
  if (n < 16384) {
    const int b = n & 63, t = n >> 6;                 // row n = t*64 + b
    const int tk = tok_src[b * 256 + t];              // input_source[b][t]
    v = *(const float4v*)(emb_src + (size_t)tk * 512 + i * 4);
  } else if (n < 16448) {
    v = *(const float4v*)(emb_tgt + (size_t)(n - 16384) * 512 + i * 4);
  }
  ushort4v o;
  o.x = f2bf(v.x); o.y = f2bf(v.y); o.z = f2bf(v.z); o.w = f2bf(v.w);
  *(ushort4v*)(A + (size_t)n * 512 + i * 4) = o;
}

// ---------------------------------------------------------------- k1w
__global__ __launch_bounds__(256)
void k1w_perm(const float* __restrict__ W, unsigned short* __restrict__ WT)
{
  const int id = blockIdx.x * 256 + threadIdx.x;  // < 786432 = 4096 * 192
  const int n  = id & 4095;                        // permuted col
  const int k0 = (id >> 12) * 8;                   // 0..1528
  const int g = n & 3, u = (n >> 2) & 3, wq = n >> 4;
  const int oc = g * 1024 + 4 * wq + u;
  short8 o;
#pragma unroll
  for (int j = 0; j < 8; ++j)
    o[j] = (short)f2bf(W[(size_t)(k0 + j) * 4096 + oc]);
  *(short8*)(WT + (size_t)n * 1536 + k0) = o;
}

// ---------------------------------------------------------------- k1p
__global__ __launch_bounds__(256)
void k1p_perm(const float* __restrict__ W, unsigned short* __restrict__ WT)
{
  const int id = blockIdx.x * 256 + threadIdx.x;  // < 8192 = 64 * 128
  const int n  = id & 63;
  const int k0 = (id >> 6) * 8;
  short8 o;
#pragma unroll
  for (int j = 0; j < 8; ++j)
    o[j] = (short)f2bf(W[(size_t)(k0 + j) * 64 + n]);
  *(short8*)(WT + (size_t)n * 1024 + k0) = o;
}

// ---------------------------------------------------------------- k2
// Zx[16512][4096] = A[16512][512] @ Wx (B given transposed: WT[4096][1536], k<512)
__global__ __launch_bounds__(256, 1)
void k2_gemm(const unsigned short* __restrict__ A,
             const unsigned short* __restrict__ BT,
             unsigned short* __restrict__ C)
{
  __shared__ __align__(16) unsigned short As[128 * 40];  // +8 bf16 pad per row
  __shared__ __align__(16) unsigned short Bs[128 * 40];
  const int tid = threadIdx.x;
  const int n0 = blockIdx.x * 128;   // 32 blocks
  const int m0 = blockIdx.y * 128;   // 129 blocks
  const int wv = tid >> 6, lane = tid & 63;
  const int wr = wv & 1, wc = wv >> 1;
  const int q = lane >> 4, l15 = lane & 15;
  f32x4 acc[4][4];
#pragma unroll
  for (int a = 0; a < 4; ++a)
#pragma unroll
    for (int b = 0; b < 4; ++b)
      acc[a][b] = (f32x4){0.f, 0.f, 0.f, 0.f};

  for (int kt = 0; kt < 16; ++kt) {   // K = 512, BK = 32
    __syncthreads();
#pragma unroll
    for (int s = 0; s < 2; ++s) {
      const int ci = tid + s * 256;          // 512 chunks of 16B
      const int row = ci >> 2, kc = ci & 3;
      *(short8*)(&As[row * 40 + kc * 8]) =
          *(const short8*)(A + (size_t)(m0 + row) * 512 + kt * 32 + kc * 8);
      *(short8*)(&Bs[row * 40 + kc * 8]) =
          *(const short8*)(BT + (size_t)(n0 + row) * 1536 + kt * 32 + kc * 8);
    }
    __syncthreads();
    short8 af[4], bf[4];
#pragma unroll
    for (int i = 0; i < 4; ++i) {
      af[i] = *(const short8*)(&As[(wr * 64 + i * 16 + l15) * 40 + q * 8]);
      bf[i] = *(const short8*)(&Bs[(wc * 64 + i * 16 + l15) * 40 + q * 8]);
    }
#pragma unroll
    for (int mi = 0; mi < 4; ++mi)
#pragma unroll
      for (int ni = 0; ni < 4; ++ni)
        acc[mi][ni] = MFMA16(af[mi], bf[ni], acc[mi][ni]);
  }
  // C/D layout: col = lane&15, row = quad*4 + i
#pragma unroll
  for (int mi = 0; mi < 4; ++mi)
#pragma unroll
    for (int ni = 0; ni < 4; ++ni)
#pragma unroll
      for (int i = 0; i < 4; ++i) {
        const int row = m0 + wr * 64 + mi * 16 + q * 4 + i;
        const int col = n0 + wc * 64 + ni * 16 + l15;
        C[(size_t)row * 4096 + col] = f2bf(acc[mi][ni][i]);
      }
}

// ---------------------------------------------------------------- k3 barrier
__device__ __forceinline__ void grid_barrier(int* flags, int w, int tid, int ph)
{
  __syncthreads();   // drains vmcnt: this WG's h stores are in L2
  if (tid == 0)
    __hip_atomic_store(&flags[w], ph, __ATOMIC_RELEASE, __HIP_MEMORY_SCOPE_AGENT);
  if (tid < 64) {
#pragma unroll
    for (int f0 = 0; f0 < 4; ++f0) {
      const int f = f0 * 64 + tid;
      while (__hip_atomic_load(&flags[f], __ATOMIC_ACQUIRE, __HIP_MEMORY_SCOPE_AGENT) < ph)
        __builtin_amdgcn_s_sleep(1);
    }
  }
  __syncthreads();
}

// ---------------------------------------------------------------- k3
// Persistent recurrent kernel: 256 WGs x 256 threads, 512 steps.
// WG w owns hidden units 4w..4w+3 (16 permuted gate cols). Wave m handles
// batch rows 16m..16m+15. c-state lives in 1 VGPR per lane across all steps.
__global__ __launch_bounds__(256, 1)
void k3_rnn(const unsigned short* __restrict__ Zx,
            const unsigned short* __restrict__ WT,
            const float* __restrict__ b_lstm,
            const int* __restrict__ tok_tgt,
            unsigned short* __restrict__ hbuf,     // 2 x [64][1024] bf16
            unsigned short* __restrict__ hs,       // [256][64][1024] bf16 (decoder outs)
            int* __restrict__ flags)
{
  __shared__ __align__(16) unsigned short Wlds[16 * 1032];  // [16 cols][1024 k], +8 pad
  __shared__ float ztile[4 * 16 * 17];                      // per-wave 16x16 (+1 pad)
  const int w = blockIdx.x;
  const int tid = threadIdx.x;
  const int wv = tid >> 6, lane = tid & 63;

  // Stage W_h slice (k rows 512..1535 of WT) into LDS, bank-conflict-padded.
  {
    const unsigned short* src = WT + (size_t)(w * 16) * 1536 + 512;
    for (int i = tid; i < 2048; i += 256) {        // 16 cols x 128 chunks
      const int c = i >> 7, kc = i & 127;
      *(short8*)(&Wlds[c * 1032 + kc * 8]) =
          *(const short8*)(src + (size_t)c * 1536 + kc * 8);
    }
  }
  // Zero both h buffers (this WG's unit slice only).
  for (int i = tid; i < 512; i += 256) {
    const int buf = i >> 8, rem = i & 255, r = rem >> 2, u = rem & 3;
    hbuf[buf * 65536 + r * 1024 + 4 * w + u] = 0;
  }
  // Gate-phase lane mapping: 64 lanes = 16 rows x 4 units.
  const int gr = lane >> 2, gu = lane & 3;
  const int rglob = wv * 16 + gr;
  const float bias0 = b_lstm[4 * w + gu];                  // i
  const float bias1 = b_lstm[1024 + 4 * w + gu];           // j
  const float bias2 = b_lstm[2048 + 4 * w + gu] + 1.0f;    // f + forget_bias
  const float bias3 = b_lstm[3072 + 4 * w + gu];           // o
  float cst = 0.f;                                         // c[rglob][4w+gu]
  // MFMA-phase lane mapping.
  const int q = lane >> 4, m15 = lane & 15;
  const int arow = wv * 16 + m15;
  float* const zt_w = &ztile[wv * 272];
  const unsigned short* const bbase = &Wlds[m15 * 1032 + q * 8];

  __syncthreads();
  int ph = 1;
  grid_barrier(flags, w, tid, ph);

  for (int t = 0; t < 512; ++t) {
    const unsigned short* hcur = hbuf + ((t & 1) ? 65536 : 0);
    unsigned short* hnxt = hbuf + ((t & 1) ? 0 : 65536);

    // z_tile[16 rows][16 cols] = h[16 rows][1024] @ Wh_slice[1024][16]
    f32x4 acc = {0.f, 0.f, 0.f, 0.f};
    const unsigned short* aptr = hcur + arow * 1024 + q * 8;
#pragma unroll 8
    for (int kt = 0; kt < 32; ++kt) {
      const short8 af = *(const short8*)(aptr + kt * 32);
      const short8 bf = *(const short8*)(bbase + kt * 32);
      acc = MFMA16(af, bf, acc);
    }
    // Transpose through wave-private LDS: C-layout -> (row, unit) lanes.
#pragma unroll
    for (int i = 0; i < 4; ++i)
      zt_w[(q * 4 + i) * 17 + m15] = acc[i];
    const float* zr = zt_w + gr * 17 + gu * 4;   // cols u*4 + (0..3) = gates i,j,f,o
    float z0 = zr[0], z1 = zr[1], z2 = zr[2], z3 = zr[3];

    // x contribution: encoder reads Zx row t*64+b; decoder reads the 64-row table.
    size_t xrow;
    if (t < 256) xrow = (size_t)(t * 64 + rglob);
    else         xrow = (size_t)(16384 + tok_tgt[rglob * 256 + (t - 256)]);
    const ushort4v zx4 = *(const ushort4v*)(Zx + xrow * 4096 + w * 16 + gu * 4);
    z0 += bf2f(zx4.x) + bias0;
    z1 += bf2f(zx4.y) + bias1;
    z2 += bf2f(zx4.z) + bias2;
    z3 += bf2f(zx4.w) + bias3;

    const float ig = sigf(z0);
    const float jg = tanhf_fast(z1);
    const float fg = sigf(z2);
    const float og = sigf(z3);
    cst = fg * cst + ig * jg;
    const float hv = og * tanhf_fast(cst);
    const unsigned short hb = f2bf(hv);
    hnxt[rglob * 1024 + 4 * w + gu] = hb;
    if (t >= 256)
      hs[((size_t)(t - 256) * 64 + rglob) * 1024 + 4 * w + gu] = hb;

    grid_barrier(flags, w, tid, ++ph);
  }
}

// ---------------------------------------------------------------- k4
// out[b][t][v] = softmax_v( hs[t][b][:] @ W_proj + b_proj )
__global__ __launch_bounds__(256, 1)
void k4_proj(const unsigned short* __restrict__ hs,
             const unsigned short* __restrict__ WT,   // WprojT [64][1024]
             const float* __restrict__ b_proj,
             float* __restrict__ out)
{
  __shared__ __align__(16) unsigned short Wl[64 * 264];  // K-split: 256 k + 8 pad
  __shared__ float zb[4 * 16 * 68];
  const int tid = threadIdx.x;
  const int wv = tid >> 6, lane = tid & 63;
  const int q = lane >> 4, m = lane & 15;
  const int row0 = blockIdx.x * 64 + wv * 16;
  f32x4 acc[4];
#pragma unroll
  for (int nt = 0; nt < 4; ++nt) acc[nt] = (f32x4){0.f, 0.f, 0.f, 0.f};

  for (int kp = 0; kp < 4; ++kp) {
    __syncthreads();
    for (int i = tid; i < 64 * 32; i += 256) {
      const int n = i >> 5, kc = i & 31;
      *(short8*)(&Wl[n * 264 + kc * 8]) =
          *(const short8*)(WT + (size_t)n * 1024 + kp * 256 + kc * 8);
    }
    __syncthreads();
    const unsigned short* aptr = hs + (size_t)(row0 + m) * 1024 + kp * 256 + q * 8;
#pragma unroll 2
    for (int kt = 0; kt < 8; ++kt) {
      const short8 af = *(const short8*)(aptr + kt * 32);
#pragma unroll
      for (int nt = 0; nt < 4; ++nt) {
        const short8 bf = *(const short8*)(&Wl[(nt * 16 + m) * 264 + kt * 32 + q * 8]);
        acc[nt] = MFMA16(af, bf, acc[nt]);
      }
    }
  }
  float* z = &zb[wv * (16 * 68)];
#pragma unroll
  for (int nt = 0; nt < 4; ++nt)
#pragma unroll
    for (int i = 0; i < 4; ++i)
      z[(q * 4 + i) * 68 + nt * 16 + m] = acc[nt][i];
  // Softmax: lane -> (row r, 16-col segment s); reduce across 4 lanes per row.
  const int r = lane >> 2, s = lane & 3;
  const float* zrow = z + r * 68 + s * 16;
  float v[16];
  float mx = -1e30f;
#pragma unroll
  for (int j = 0; j < 16; ++j) {
    v[j] = zrow[j] + b_proj[s * 16 + j];
    mx = fmaxf(mx, v[j]);
  }
  mx = fmaxf(mx, __shfl_xor(mx, 1));
  mx = fmaxf(mx, __shfl_xor(mx, 2));
  float sum = 0.f;
#pragma unroll
  for (int j = 0; j < 16; ++j) { v[j] = __expf(v[j] - mx); sum += v[j]; }
  sum += __shfl_xor(sum, 1);
  sum += __shfl_xor(sum, 2);
  const float inv = 1.0f / sum;
  const int nrow = row0 + r;
  const int b = nrow & 63, t = nrow >> 6;
  float* op = out + ((size_t)b * 256 + t) * 64 + s * 16;
#pragma unroll
  for (int x = 0; x < 4; ++x) {
    const float4v o4 = { v[4 * x] * inv, v[4 * x + 1] * inv,
                         v[4 * x + 2] * inv, v[4 * x + 3] * inv };
    *(float4v*)(op + 4 * x) = o4;
  }
}

// ---------------------------------------------------------------- launch
extern "C" void kernel_launch(void* const* d_in, const int* in_sizes, int n_in,
                              void* d_out, int out_size, void* d_ws, size_t ws_size,
                              hipStream_t stream)
{
  const int*   tok_src = (const int*)d_in[0];
  const int*   tok_tgt = (const int*)d_in[1];
  const float* emb_src = (const float*)d_in[2];
  const float* emb_tgt = (const float*)d_in[3];
  const float* W_lstm  = (const float*)d_in[4];
  const float* b_lstm  = (const float*)d_in[5];
  const float* W_proj  = (const float*)d_in[6];
  const float* b_proj  = (const float*)d_in[7];
  float* out = (float*)d_out;

  char* ws = (char*)d_ws;
  size_t off = 0;
  int* flags            = (int*)(ws + off);            off += 4096;
  unsigned short* A     = (unsigned short*)(ws + off); off += (size_t)16512 * 512 * 2;
  unsigned short* WT    = (unsigned short*)(ws + off); off += (size_t)4096 * 1536 * 2;
  unsigned short* WPT   = (unsigned short*)(ws + off); off += (size_t)64 * 1024 * 2;
  unsigned short* Zx    = (unsigned short*)(ws + off); off += (size_t)16512 * 4096 * 2;
  unsigned short* hbuf  = (unsigned short*)(ws + off); off += (size_t)2 * 64 * 1024 * 2;
  unsigned short* hs    = (unsigned short*)(ws + off); off += (size_t)16384 * 1024 * 2;
  if (ws_size < off) return;  // insufficient workspace -> loud correctness failure

  hipMemsetAsync(flags, 0, 4096, stream);
  hipLaunchKernelGGL(k1a_gather, dim3(16512), dim3(128), 0, stream, tok_src, emb_src, emb_tgt, A);
  hipLaunchKernelGGL(k1w_perm,   dim3(3072),  dim3(256), 0, stream, W_lstm, WT);
  hipLaunchKernelGGL(k1p_perm,   dim3(32),    dim3(256), 0, stream, W_proj, WPT);
  hipLaunchKernelGGL(k2_gemm,    dim3(32, 129), dim3(256), 0, stream, A, WT, Zx);
  hipLaunchKernelGGL(k3_rnn,     dim3(256),   dim3(256), 0, stream, Zx, WT, b_lstm, tok_tgt, hbuf, hs, flags);
  hipLaunchKernelGGL(k4_proj,    dim3(256),   dim3(256), 0, stream, hs, WPT, b_proj, out);
}

// Round 3
// 5186.635 us; speedup vs baseline: 2.3308x; 2.3308x over previous
//
#include <hip/hip_runtime.h>

// Seq2seq LSTM (B=64, T=256, E=512, H=1024, V_TGT=64) on gfx950.
//   k1a: gather+convert A_bf16[16512][512]
//   k1w: W_lstm fp32 [1536][4096] -> WpermT bf16 [4096][1536] (col-permuted)
//   k1p: W_proj -> WprojT bf16 [64][1024]
//   k2 : Zx bf16 [16512][4096] = A @ Wx
//   k3 : persistent 256-WG recurrence, FENCE-FREE protocol: every cross-WG
//        datum (h, flags) is accessed ONLY via relaxed agent-scope atomics
//        (sc1 -> serviced at the cross-XCD-coherent LLC). No buffer_wbl2 /
//        buffer_inv per step. Round-2 hang root cause: flag store was
//        workgroup-scope (normal writeback store, dirty in local L2, never
//        visible at LLC) -> consumers spun forever. Fixed: relaxed AGENT
//        store, ordered by explicit s_waitcnt vmcnt(0) + barrier.
//   k4 : projection + softmax -> d_out fp32 [64][256][64]

typedef __attribute__((ext_vector_type(8))) short short8;        // bf16 frag
typedef __attribute__((ext_vector_type(4))) float f32x4;         // MFMA acc
typedef __attribute__((ext_vector_type(4))) float float4v;
typedef __attribute__((ext_vector_type(4))) unsigned short ushort4v;

#define MFMA16(A, B, C) __builtin_amdgcn_mfma_f32_16x16x32_bf16((A), (B), (C), 0, 0, 0)
#define WAIT_VM0() __builtin_amdgcn_s_waitcnt(0x0F70)   // vmcnt(0), ignore exp/lgkm
#define COMPILER_FENCE() asm volatile("" ::: "memory")

__device__ __forceinline__ unsigned short f2bf(float f) {
  union { float f; unsigned u; } v; v.f = f;
  unsigned r = (v.u + 0x7fffu + ((v.u >> 16) & 1u)) >> 16;   // RNE, no NaN in data
  return (unsigned short)r;
}
__device__ __forceinline__ float bf2f(unsigned short h) {
  union { unsigned u; float f; } v; v.u = ((unsigned)h) << 16;
  return v.f;
}
__device__ __forceinline__ float sigf(float x) { return 1.0f / (1.0f + __expf(-x)); }
__device__ __forceinline__ float tanhf_fast(float x) { return 1.0f - 2.0f / (1.0f + __expf(2.0f * x)); }

// ---------------------------------------------------------------- k1a
__global__ __launch_bounds__(128)
void k1a_gather(const int* __restrict__ tok_src,
                const float* __restrict__ emb_src,
                const float* __restrict__ emb_tgt,
                unsigned short* __restrict__ A)
{
  const int n = blockIdx.x;     // 0..16511
  const int i = threadIdx.x;    // 0..127, each does 4 elements
  float4v v = {0.f, 0.f, 0.f, 0.f};
  if (n < 16384) {
    const int b = n & 63, t = n >> 6;                 // row n = t*64 + b
    const int tk = tok_src[b * 256 + t];              // input_source[b][t]
    v = *(const float4v*)(emb_src + (size_t)tk * 512 + i * 4);
  } else if (n < 16448) {
    v = *(const float4v*)(emb_tgt + (size_t)(n - 16384) * 512 + i * 4);
  }
  ushort4v o;
  o.x = f2bf(v.x); o.y = f2bf(v.y); o.z = f2bf(v.z); o.w = f2bf(v.w);
  *(ushort4v*)(A + (size_t)n * 512 + i * 4) = o;
}

// ---------------------------------------------------------------- k1w
__global__ __launch_bounds__(256)
void k1w_perm(const float* __restrict__ W, unsigned short* __restrict__ WT)
{
  const int id = blockIdx.x * 256 + threadIdx.x;  // < 786432 = 4096 * 192
  const int n  = id & 4095;                        // permuted col
  const int k0 = (id >> 12) * 8;                   // 0..1528
  const int g = n & 3, u = (n >> 2) & 3, wq = n >> 4;
  const int oc = g * 1024 + 4 * wq + u;
  short8 o;
#pragma unroll
  for (int j = 0; j < 8; ++j)
    o[j] = (short)f2bf(W[(size_t)(k0 + j) * 4096 + oc]);
  *(short8*)(WT + (size_t)n * 1536 + k0) = o;
}

// ---------------------------------------------------------------- k1p
__global__ __launch_bounds__(256)
void k1p_perm(const float* __restrict__ W, unsigned short* __restrict__ WT)
{
  const int id = blockIdx.x * 256 + threadIdx.x;  // < 8192 = 64 * 128
  const int n  = id & 63;
  const int k0 = (id >> 6) * 8;
  short8 o;
#pragma unroll
  for (int j = 0; j < 8; ++j)
    o[j] = (short)f2bf(W[(size_t)(k0 + j) * 64 + n]);
  *(short8*)(WT + (size_t)n * 1024 + k0) = o;
}

// ---------------------------------------------------------------- k2
__global__ __launch_bounds__(256, 1)
void k2_gemm(const unsigned short* __restrict__ A,
             const unsigned short* __restrict__ BT,
             unsigned short* __restrict__ C)
{
  __shared__ __align__(16) unsigned short As[128 * 40];
  __shared__ __align__(16) unsigned short Bs[128 * 40];
  const int tid = threadIdx.x;
  const int n0 = blockIdx.x * 128;   // 32 blocks
  const int m0 = blockIdx.y * 128;   // 129 blocks
  const int wv = tid >> 6, lane = tid & 63;
  const int wr = wv & 1, wc = wv >> 1;
  const int q = lane >> 4, l15 = lane & 15;
  f32x4 acc[4][4];
#pragma unroll
  for (int a = 0; a < 4; ++a)
#pragma unroll
    for (int b = 0; b < 4; ++b)
      acc[a][b] = (f32x4){0.f, 0.f, 0.f, 0.f};

  for (int kt = 0; kt < 16; ++kt) {   // K = 512, BK = 32
    __syncthreads();
#pragma unroll
    for (int s = 0; s < 2; ++s) {
      const int ci = tid + s * 256;
      const int row = ci >> 2, kc = ci & 3;
      *(short8*)(&As[row * 40 + kc * 8]) =
          *(const short8*)(A + (size_t)(m0 + row) * 512 + kt * 32 + kc * 8);
      *(short8*)(&Bs[row * 40 + kc * 8]) =
          *(const short8*)(BT + (size_t)(n0 + row) * 1536 + kt * 32 + kc * 8);
    }
    __syncthreads();
    short8 af[4], bf[4];
#pragma unroll
    for (int i = 0; i < 4; ++i) {
      af[i] = *(const short8*)(&As[(wr * 64 + i * 16 + l15) * 40 + q * 8]);
      bf[i] = *(const short8*)(&Bs[(wc * 64 + i * 16 + l15) * 40 + q * 8]);
    }
#pragma unroll
    for (int mi = 0; mi < 4; ++mi)
#pragma unroll
      for (int ni = 0; ni < 4; ++ni)
        acc[mi][ni] = MFMA16(af[mi], bf[ni], acc[mi][ni]);
  }
#pragma unroll
  for (int mi = 0; mi < 4; ++mi)
#pragma unroll
    for (int ni = 0; ni < 4; ++ni)
#pragma unroll
      for (int i = 0; i < 4; ++i) {
        const int row = m0 + wr * 64 + mi * 16 + q * 4 + i;
        const int col = n0 + wc * 64 + ni * 16 + l15;
        C[(size_t)row * 4096 + col] = f2bf(acc[mi][ni][i]);
      }
}

// ---------------------------------------------------------------- k3
// Fence-free persistent recurrence. 256 WGs x 256 threads, 512 steps.
// WG w owns hidden units 4w..4w+3. Wave m handles batch rows 16m..16m+15.
__global__ __launch_bounds__(256, 1)
void k3_rnn(const unsigned short* __restrict__ Zx,
            const unsigned short* __restrict__ WT,
            const float* __restrict__ b_lstm,
            const int* __restrict__ tok_tgt,
            unsigned int* __restrict__ hbuf,     // 2 x [64][512] dwords (bf16 x2)
            unsigned int* __restrict__ hs,       // [256][64][512] dwords
            int* __restrict__ flags)             // [256] step counters, 64B stride
{
  __shared__ __align__(16) unsigned short Wlds[16 * 1032];  // [16 cols][1024 k] +8 pad
  __shared__ float ztile[4 * 16 * 17];                      // per-wave 16x16 (+1 pad)
  const int w = blockIdx.x;
  const int tid = threadIdx.x;
  const int wv = tid >> 6, lane = tid & 63;

  // Stage W_h slice (k rows 512..1535 of WT) into LDS.
  {
    const unsigned short* src = WT + (size_t)(w * 16) * 1536 + 512;
    for (int i = tid; i < 2048; i += 256) {
      const int c = i >> 7, kc = i & 127;
      *(short8*)(&Wlds[c * 1032 + kc * 8]) =
          *(const short8*)(src + (size_t)c * 1536 + kc * 8);
    }
  }
  // Zero h buffer 0 (this WG's unit slice) via write-through sc1 stores.
  if (tid < 128) {
    const int r = tid >> 1, d = tid & 1;
    __hip_atomic_store(&hbuf[r * 512 + w * 2 + d], 0u,
                       __ATOMIC_RELAXED, __HIP_MEMORY_SCOPE_AGENT);
  }
  // Gate-phase lane mapping: 64 lanes = 16 rows x 4 units.
  const int gr = lane >> 2, gu = lane & 3;
  const int rglob = wv * 16 + gr;
  const float bias0 = b_lstm[4 * w + gu];                  // i
  const float bias1 = b_lstm[1024 + 4 * w + gu];           // j
  const float bias2 = b_lstm[2048 + 4 * w + gu] + 1.0f;    // f + forget_bias
  const float bias3 = b_lstm[3072 + 4 * w + gu];           // o
  float cst = 0.f;
  // MFMA-phase lane mapping.
  const int q = lane >> 4, m15 = lane & 15;
  const int arow = wv * 16 + m15;
  float* const zt_w = &ztile[wv * 272];
  const unsigned short* const bbase = &Wlds[m15 * 1032 + q * 8];

  COMPILER_FENCE();
  WAIT_VM0();            // hbuf zero-stores ACKed at LLC
  COMPILER_FENCE();
  __syncthreads();
  if (tid == 0)
    __hip_atomic_store(&flags[w * 16], 1, __ATOMIC_RELAXED, __HIP_MEMORY_SCOPE_AGENT);

  int* const myflag = &flags[tid * 16];
  bool dead = false;

  for (int t = 0; t < 512 && !dead; ++t) {
    // Barrier-in: h_t ready everywhere <=> all flags >= t+1.
    {
      int spin = 0;
      while (__hip_atomic_load(myflag, __ATOMIC_RELAXED, __HIP_MEMORY_SCOPE_AGENT) < t + 1) {
        __builtin_amdgcn_s_sleep(2);
        if (++spin > (1 << 20)) { dead = true; break; }   // ~50 ms escape hatch
      }
    }
    COMPILER_FENCE();
    __syncthreads();

    const unsigned long long* hp =
        (const unsigned long long*)(hbuf + ((t & 1) ? 32768 : 0)) + arow * 256 + q * 2;
    unsigned int* hnxt = hbuf + ((t & 1) ? 0 : 32768);

    // z_tile = h[16 rows][1024] @ Wh_slice[1024][16]; A-frags straight from LLC.
    f32x4 acc = {0.f, 0.f, 0.f, 0.f};
#pragma unroll
    for (int half = 0; half < 2; ++half) {
      unsigned long long h0[16], h1[16];
#pragma unroll
      for (int b = 0; b < 16; ++b) {
        const unsigned long long* p = hp + (size_t)(half * 16 + b) * 8;
        h0[b] = __hip_atomic_load(p,     __ATOMIC_RELAXED, __HIP_MEMORY_SCOPE_AGENT);
        h1[b] = __hip_atomic_load(p + 1, __ATOMIC_RELAXED, __HIP_MEMORY_SCOPE_AGENT);
      }
#pragma unroll
      for (int b = 0; b < 16; ++b) {
        union { unsigned long long u[2]; short8 s; } cv;
        cv.u[0] = h0[b]; cv.u[1] = h1[b];
        const short8 bfr = *(const short8*)(bbase + (half * 16 + b) * 32);
        acc = MFMA16(cv.s, bfr, acc);
      }
    }
    // Transpose through wave-private LDS: C-layout -> (row, unit) lanes.
#pragma unroll
    for (int i = 0; i < 4; ++i)
      zt_w[(q * 4 + i) * 17 + m15] = acc[i];
    __builtin_amdgcn_s_waitcnt(0xC07F);   // lgkmcnt(0)
    const float* zr = zt_w + gr * 17 + gu * 4;
    float z0 = zr[0], z1 = zr[1], z2 = zr[2], z3 = zr[3];

    // x contribution.
    size_t xrow;
    if (t < 256) xrow = (size_t)(t * 64 + rglob);
    else         xrow = (size_t)(16384 + tok_tgt[rglob * 256 + (t - 256)]);
    const ushort4v zx4 = *(const ushort4v*)(Zx + xrow * 4096 + w * 16 + gu * 4);
    z0 += bf2f(zx4.x) + bias0;
    z1 += bf2f(zx4.y) + bias1;
    z2 += bf2f(zx4.z) + bias2;
    z3 += bf2f(zx4.w) + bias3;

    const float ig = sigf(z0);
    const float jg = tanhf_fast(z1);
    const float fg = sigf(z2);
    const float og = sigf(z3);
    cst = fg * cst + ig * jg;
    const float hv = og * tanhf_fast(cst);
    const unsigned short hb = f2bf(hv);

    // Pack two adjacent units into one dword; lanes gu=0,2 store.
    const unsigned int partner = (unsigned int)(unsigned short)__shfl_down((int)hb, 1);
    const unsigned int hpack = (unsigned int)hb | (partner << 16);
    const int dwi = rglob * 512 + w * 2 + (gu >> 1);
    if ((gu & 1) == 0) {
      __hip_atomic_store(&hnxt[dwi], hpack, __ATOMIC_RELAXED, __HIP_MEMORY_SCOPE_AGENT);
      if (t >= 256)
        hs[(size_t)(t - 256) * 32768 + dwi] = hpack;   // normal store, read by k4
    }

    // Barrier-out: drain own sc1 stores to LLC, then publish flag (sc1 store).
    COMPILER_FENCE();
    WAIT_VM0();
    COMPILER_FENCE();
    __syncthreads();
    if (tid == 0)
      __hip_atomic_store(&flags[w * 16], t + 2, __ATOMIC_RELAXED, __HIP_MEMORY_SCOPE_AGENT);
  }
}

// ---------------------------------------------------------------- k4
__global__ __launch_bounds__(256, 1)
void k4_proj(const unsigned short* __restrict__ hs,
             const unsigned short* __restrict__ WT,   // WprojT [64][1024]
             const float* __restrict__ b_proj,
             float* __restrict__ out)
{
  __shared__ __align__(16) unsigned short Wl[64 * 264];
  __shared__ float zb[4 * 16 * 68];
  const int tid = threadIdx.x;
  const int wv = tid >> 6, lane = tid & 63;
  const int q = lane >> 4, m = lane & 15;
  const int row0 = blockIdx.x * 64 + wv * 16;
  f32x4 acc[4];
#pragma unroll
  for (int nt = 0; nt < 4; ++nt) acc[nt] = (f32x4){0.f, 0.f, 0.f, 0.f};

  for (int kp = 0; kp < 4; ++kp) {
    __syncthreads();
    for (int i = tid; i < 64 * 32; i += 256) {
      const int n = i >> 5, kc = i & 31;
      *(short8*)(&Wl[n * 264 + kc * 8]) =
          *(const short8*)(WT + (size_t)n * 1024 + kp * 256 + kc * 8);
    }
    __syncthreads();
    const unsigned short* aptr = hs + (size_t)(row0 + m) * 1024 + kp * 256 + q * 8;
#pragma unroll 2
    for (int kt = 0; kt < 8; ++kt) {
      const short8 af = *(const short8*)(aptr + kt * 32);
#pragma unroll
      for (int nt = 0; nt < 4; ++nt) {
        const short8 bfr = *(const short8*)(&Wl[(nt * 16 + m) * 264 + kt * 32 + q * 8]);
        acc[nt] = MFMA16(af, bfr, acc[nt]);
      }
    }
  }
  float* z = &zb[wv * (16 * 68)];
#pragma unroll
  for (int nt = 0; nt < 4; ++nt)
#pragma unroll
    for (int i = 0; i < 4; ++i)
      z[(q * 4 + i) * 68 + nt * 16 + m] = acc[nt][i];
  __syncthreads();
  const int r = lane >> 2, s = lane & 3;
  const float* zrow = z + r * 68 + s * 16;
  float v[16];
  float mx = -1e30f;
#pragma unroll
  for (int j = 0; j < 16; ++j) {
    v[j] = zrow[j] + b_proj[s * 16 + j];
    mx = fmaxf(mx, v[j]);
  }
  mx = fmaxf(mx, __shfl_xor(mx, 1));
  mx = fmaxf(mx, __shfl_xor(mx, 2));
  float sum = 0.f;
#pragma unroll
  for (int j = 0; j < 16; ++j) { v[j] = __expf(v[j] - mx); sum += v[j]; }
  sum += __shfl_xor(sum, 1);
  sum += __shfl_xor(sum, 2);
  const float inv = 1.0f / sum;
  const int nrow = row0 + r;
  const int b = nrow & 63, t = nrow >> 6;
  float* op = out + ((size_t)b * 256 + t) * 64 + s * 16;
#pragma unroll
  for (int x = 0; x < 4; ++x) {
    const float4v o4 = { v[4 * x] * inv, v[4 * x + 1] * inv,
                         v[4 * x + 2] * inv, v[4 * x + 3] * inv };
    *(float4v*)(op + 4 * x) = o4;
  }
}

// ---------------------------------------------------------------- launch
extern "C" void kernel_launch(void* const* d_in, const int* in_sizes, int n_in,
                              void* d_out, int out_size, void* d_ws, size_t ws_size,
                              hipStream_t stream)
{
  const int*   tok_src = (const int*)d_in[0];
  const int*   tok_tgt = (const int*)d_in[1];
  const float* emb_src = (const float*)d_in[2];
  const float* emb_tgt = (const float*)d_in[3];
  const float* W_lstm  = (const float*)d_in[4];
  const float* b_lstm  = (const float*)d_in[5];
  const float* W_proj  = (const float*)d_in[6];
  const float* b_proj  = (const float*)d_in[7];
  float* out = (float*)d_out;

  char* ws = (char*)d_ws;
  size_t off = 0;
  int* flags            = (int*)(ws + off);            off += 16384;  // 256 x 64B
  unsigned short* A     = (unsigned short*)(ws + off); off += (size_t)16512 * 512 * 2;
  unsigned short* WT    = (unsigned short*)(ws + off); off += (size_t)4096 * 1536 * 2;
  unsigned short* WPT   = (unsigned short*)(ws + off); off += (size_t)64 * 1024 * 2;
  unsigned short* Zx    = (unsigned short*)(ws + off); off += (size_t)16512 * 4096 * 2;
  unsigned int* hbuf    = (unsigned int*)(ws + off);   off += (size_t)2 * 64 * 512 * 4;
  unsigned int* hs      = (unsigned int*)(ws + off);   off += (size_t)256 * 64 * 512 * 4;
  if (ws_size < off) return;  // insufficient workspace -> loud correctness failure

  hipMemsetAsync(flags, 0, 16384, stream);
  hipLaunchKernelGGL(k1a_gather, dim3(16512), dim3(128), 0, stream, tok_src, emb_src, emb_tgt, A);
  hipLaunchKernelGGL(k1w_perm,   dim3(3072),  dim3(256), 0, stream, W_lstm, WT);
  hipLaunchKernelGGL(k1p_perm,   dim3(32),    dim3(256), 0, stream, W_proj, WPT);
  hipLaunchKernelGGL(k2_gemm,    dim3(32, 129), dim3(256), 0, stream, A, WT, Zx);
  hipLaunchKernelGGL(k3_rnn,     dim3(256),   dim3(256), 0, stream, Zx, WT, b_lstm, tok_tgt, hbuf, (unsigned int*)hs, flags);
  hipLaunchKernelGGL(k4_proj,    dim3(256),   dim3(256), 0, stream, (const unsigned short*)hs, WPT, b_proj, out);
}

// Round 4
// 4713.780 us; speedup vs baseline: 2.5646x; 1.1003x over previous
//
#include <hip/hip_runtime.h>

// Seq2seq LSTM (B=64, T=256, E=512, H=1024, V_TGT=64) on gfx950.
//   k1a: gather+convert A_bf16[16512][512]
//   k1w: W_lstm fp32 [1536][4096] -> WpermT bf16 [4096][1536] (col-permuted)
//   k1p: W_proj -> WprojT bf16 [64][1024]
//   k2 : Zx bf16 [16512][4096] = A @ Wx
//   k3 : persistent 256-WG recurrence. Round-4 structure:
//        - h flows through 512 WRITE-ONCE buffers: producers sc1-store (LLC),
//          consumers use PLAIN 16B loads -> per-XCD L2 sharing (32x less LLC
//          traffic). Safe because each buffer address is written exactly once
//          and never normal-read before that write (encoder buffers overlay
//          dead Zx regions, whose in-k3 reads are all sc1/L2-bypassing;
//          dispatch-boundary acquire invalidated all caches at k3 start).
//        - W_h slice lives in VGPRs (128/wave) -> zero per-step ds_reads.
//        - decoder chain doubles as k4's input (old hs buffer eliminated).
//   k4 : projection + softmax -> d_out fp32 [64][256][64]

typedef __attribute__((ext_vector_type(8))) short short8;        // bf16 frag
typedef __attribute__((ext_vector_type(4))) float f32x4;         // MFMA acc
typedef __attribute__((ext_vector_type(4))) float float4v;
typedef __attribute__((ext_vector_type(4))) unsigned short ushort4v;

#define MFMA16(A, B, C) __builtin_amdgcn_mfma_f32_16x16x32_bf16((A), (B), (C), 0, 0, 0)
#define WAIT_VM0() __builtin_amdgcn_s_waitcnt(0x0F70)   // vmcnt(0), ignore exp/lgkm
#define COMPILER_FENCE() asm volatile("" ::: "memory")

__device__ __forceinline__ unsigned short f2bf(float f) {
  union { float f; unsigned u; } v; v.f = f;
  unsigned r = (v.u + 0x7fffu + ((v.u >> 16) & 1u)) >> 16;   // RNE, no NaN in data
  return (unsigned short)r;
}
__device__ __forceinline__ float bf2f(unsigned short h) {
  union { unsigned u; float f; } v; v.u = ((unsigned)h) << 16;
  return v.f;
}
__device__ __forceinline__ float sigf(float x) { return 1.0f / (1.0f + __expf(-x)); }
__device__ __forceinline__ float tanhf_fast(float x) { return 1.0f - 2.0f / (1.0f + __expf(2.0f * x)); }

// Chain buffer C_t (h-state consumed at step t), t in 1..512.
//   t==1      : dedicated hbuf1 (128 KB)
//   2..256    : overlay dead Zx encoder region (t-2): byte off (t-2)*512KB
//   257..512  : dedicated decoder chain (also k4's input), 128 KB each
__device__ __forceinline__ unsigned short*
chain_ptr(unsigned short* Zx, unsigned short* hbuf1, unsigned short* chainD, int t)
{
  if (t == 1)  return hbuf1;
  if (t < 257) return Zx + (size_t)(t - 2) * 262144;
  return chainD + (size_t)(t - 257) * 65536;
}

// ---------------------------------------------------------------- k1a
__global__ __launch_bounds__(128)
void k1a_gather(const int* __restrict__ tok_src,
                const float* __restrict__ emb_src,
                const float* __restrict__ emb_tgt,
                unsigned short* __restrict__ A)
{
  const int n = blockIdx.x;     // 0..16511
  const int i = threadIdx.x;    // 0..127, each does 4 elements
  float4v v = {0.f, 0.f, 0.f, 0.f};
  if (n < 16384) {
    const int b = n & 63, t = n >> 6;                 // row n = t*64 + b
    const int tk = tok_src[b * 256 + t];              // input_source[b][t]
    v = *(const float4v*)(emb_src + (size_t)tk * 512 + i * 4);
  } else if (n < 16448) {
    v = *(const float4v*)(emb_tgt + (size_t)(n - 16384) * 512 + i * 4);
  }
  ushort4v o;
  o.x = f2bf(v.x); o.y = f2bf(v.y); o.z = f2bf(v.z); o.w = f2bf(v.w);
  *(ushort4v*)(A + (size_t)n * 512 + i * 4) = o;
}

// ---------------------------------------------------------------- k1w
__global__ __launch_bounds__(256)
void k1w_perm(const float* __restrict__ W, unsigned short* __restrict__ WT)
{
  const int id = blockIdx.x * 256 + threadIdx.x;  // < 786432 = 4096 * 192
  const int n  = id & 4095;                        // permuted col
  const int k0 = (id >> 12) * 8;                   // 0..1528
  const int g = n & 3, u = (n >> 2) & 3, wq = n >> 4;
  const int oc = g * 1024 + 4 * wq + u;
  short8 o;
#pragma unroll
  for (int j = 0; j < 8; ++j)
    o[j] = (short)f2bf(W[(size_t)(k0 + j) * 4096 + oc]);
  *(short8*)(WT + (size_t)n * 1536 + k0) = o;
}

// ---------------------------------------------------------------- k1p
__global__ __launch_bounds__(256)
void k1p_perm(const float* __restrict__ W, unsigned short* __restrict__ WT)
{
  const int id = blockIdx.x * 256 + threadIdx.x;  // < 8192 = 64 * 128
  const int n  = id & 63;
  const int k0 = (id >> 6) * 8;
  short8 o;
#pragma unroll
  for (int j = 0; j < 8; ++j)
    o[j] = (short)f2bf(W[(size_t)(k0 + j) * 64 + n]);
  *(short8*)(WT + (size_t)n * 1024 + k0) = o;
}

// ---------------------------------------------------------------- k2
__global__ __launch_bounds__(256, 1)
void k2_gemm(const unsigned short* __restrict__ A,
             const unsigned short* __restrict__ BT,
             unsigned short* __restrict__ C)
{
  __shared__ __align__(16) unsigned short As[128 * 40];
  __shared__ __align__(16) unsigned short Bs[128 * 40];
  const int tid = threadIdx.x;
  const int n0 = blockIdx.x * 128;   // 32 blocks
  const int m0 = blockIdx.y * 128;   // 129 blocks
  const int wv = tid >> 6, lane = tid & 63;
  const int wr = wv & 1, wc = wv >> 1;
  const int q = lane >> 4, l15 = lane & 15;
  f32x4 acc[4][4];
#pragma unroll
  for (int a = 0; a < 4; ++a)
#pragma unroll
    for (int b = 0; b < 4; ++b)
      acc[a][b] = (f32x4){0.f, 0.f, 0.f, 0.f};

  for (int kt = 0; kt < 16; ++kt) {   // K = 512, BK = 32
    __syncthreads();
#pragma unroll
    for (int s = 0; s < 2; ++s) {
      const int ci = tid + s * 256;
      const int row = ci >> 2, kc = ci & 3;
      *(short8*)(&As[row * 40 + kc * 8]) =
          *(const short8*)(A + (size_t)(m0 + row) * 512 + kt * 32 + kc * 8);
      *(short8*)(&Bs[row * 40 + kc * 8]) =
          *(const short8*)(BT + (size_t)(n0 + row) * 1536 + kt * 32 + kc * 8);
    }
    __syncthreads();
    short8 af[4], bf[4];
#pragma unroll
    for (int i = 0; i < 4; ++i) {
      af[i] = *(const short8*)(&As[(wr * 64 + i * 16 + l15) * 40 + q * 8]);
      bf[i] = *(const short8*)(&Bs[(wc * 64 + i * 16 + l15) * 40 + q * 8]);
    }
#pragma unroll
    for (int mi = 0; mi < 4; ++mi)
#pragma unroll
      for (int ni = 0; ni < 4; ++ni)
        acc[mi][ni] = MFMA16(af[mi], bf[ni], acc[mi][ni]);
  }
#pragma unroll
  for (int mi = 0; mi < 4; ++mi)
#pragma unroll
    for (int ni = 0; ni < 4; ++ni)
#pragma unroll
      for (int i = 0; i < 4; ++i) {
        const int row = m0 + wr * 64 + mi * 16 + q * 4 + i;
        const int col = n0 + wc * 64 + ni * 16 + l15;
        C[(size_t)row * 4096 + col] = f2bf(acc[mi][ni][i]);
      }
}

// ---------------------------------------------------------------- k3
// 256 WGs x 256 threads, 512 steps. WG w owns hidden units 4w..4w+3.
__global__ __launch_bounds__(256, 1)
void k3_rnn(unsigned short* __restrict__ Zx,
            const unsigned short* __restrict__ WT,
            const float* __restrict__ b_lstm,
            const int* __restrict__ tok_tgt,
            unsigned short* __restrict__ hbuf1,    // C_1 (128 KB)
            unsigned short* __restrict__ chainD,   // C_257..C_512 (32 MB)
            int* __restrict__ flags)               // [256] step counters, 64B stride
{
  __shared__ float ztile[4 * 16 * 17];             // per-wave 16x16 (+1 pad)
  const int w = blockIdx.x;
  const int tid = threadIdx.x;
  const int wv = tid >> 6, lane = tid & 63;

  // Gate-phase lane mapping: 64 lanes = 16 rows x 4 units.
  const int gr = lane >> 2, gu = lane & 3;
  const int rglob = wv * 16 + gr;
  const float bias0 = b_lstm[4 * w + gu];                  // i
  const float bias1 = b_lstm[1024 + 4 * w + gu];           // j
  const float bias2 = b_lstm[2048 + 4 * w + gu] + 1.0f;    // f + forget_bias
  const float bias3 = b_lstm[3072 + 4 * w + gu];           // o
  float cst = 0.f;
  // MFMA-phase lane mapping.
  const int q = lane >> 4, m15 = lane & 15;
  const int arow = wv * 16 + m15;
  float* const zt_w = &ztile[wv * 272];

  // Preload the wave's W_h B-frags into VGPRs: col w*16+m15, k 512+kt*32+q*8.
  short8 Breg[32];
  {
    const unsigned short* wsrc = WT + (size_t)(w * 16 + m15) * 1536 + 512 + q * 8;
#pragma unroll
    for (int kt = 0; kt < 32; ++kt)
      Breg[kt] = *(const short8*)(wsrc + kt * 32);
  }

  __syncthreads();
  if (tid == 0)
    __hip_atomic_store(&flags[w * 16], 1, __ATOMIC_RELAXED, __HIP_MEMORY_SCOPE_AGENT);

  int* const myflag = &flags[tid * 16];
  bool dead = false;

  for (int t = 0; t < 512 && !dead; ++t) {
    // Prefetch x-contribution (independent of the barrier).
    unsigned long long zx8;
    if (t < 256) {
      // Encoder Zx rows: sc1 (L1/L2-bypass) so overlaid chain reads stay safe.
      const size_t xrow = (size_t)(t * 64 + rglob);
      zx8 = __hip_atomic_load((const unsigned long long*)(Zx + xrow * 4096 + w * 16 + gu * 4),
                              __ATOMIC_RELAXED, __HIP_MEMORY_SCOPE_AGENT);
    } else {
      // Decoder table rows 16384+tok: never overlaid -> normal (L2-hot) load.
      const size_t xrow = (size_t)(16384 + tok_tgt[rglob * 256 + (t - 256)]);
      zx8 = *(const unsigned long long*)(Zx + xrow * 4096 + w * 16 + gu * 4);
    }

    // Barrier-in: C_t fully published <=> all flags >= t+1.
    {
      int spin = 0;
      while (__hip_atomic_load(myflag, __ATOMIC_RELAXED, __HIP_MEMORY_SCOPE_AGENT) < t + 1) {
        __builtin_amdgcn_s_sleep(1);
        if (++spin > (1 << 21)) { dead = true; break; }   // escape hatch
      }
    }
    COMPILER_FENCE();
    __syncthreads();

    // z_tile = h[16 rows][1024] @ Wh_slice[1024][16]; h via plain 16B loads
    // (write-once buffer: correct value is the only value these lines can hold).
    f32x4 acc0 = {0.f, 0.f, 0.f, 0.f};
    f32x4 acc1 = {0.f, 0.f, 0.f, 0.f};
    if (t > 0) {
      const unsigned short* hb = chain_ptr(Zx, hbuf1, chainD, t);
      const unsigned short* ap = hb + arow * 1024 + q * 8;
#pragma unroll
      for (int kt = 0; kt < 16; ++kt) {
        const short8 a0 = *(const short8*)(ap + kt * 32);
        const short8 a1 = *(const short8*)(ap + (kt + 16) * 32);
        acc0 = MFMA16(a0, Breg[kt], acc0);
        acc1 = MFMA16(a1, Breg[kt + 16], acc1);
      }
    }
    // Transpose through wave-private LDS: C-layout -> (row, unit) lanes.
#pragma unroll
    for (int i = 0; i < 4; ++i)
      zt_w[(q * 4 + i) * 17 + m15] = acc0[i] + acc1[i];
    __builtin_amdgcn_s_waitcnt(0xC07F);   // lgkmcnt(0)
    const float* zr = zt_w + gr * 17 + gu * 4;
    float z0 = zr[0], z1 = zr[1], z2 = zr[2], z3 = zr[3];

    z0 += bf2f((unsigned short)(zx8 >> 0))  + bias0;
    z1 += bf2f((unsigned short)(zx8 >> 16)) + bias1;
    z2 += bf2f((unsigned short)(zx8 >> 32)) + bias2;
    z3 += bf2f((unsigned short)(zx8 >> 48)) + bias3;

    const float ig = sigf(z0);
    const float jg = tanhf_fast(z1);
    const float fg = sigf(z2);
    const float og = sigf(z3);
    cst = fg * cst + ig * jg;
    const float hv = og * tanhf_fast(cst);
    const unsigned short hb16 = f2bf(hv);

    // Pack two adjacent units into one dword; lanes gu=0,2 sc1-store to C_{t+1}.
    const unsigned int partner = (unsigned int)(unsigned short)__shfl_down((int)hb16, 1);
    const unsigned int hpack = (unsigned int)hb16 | (partner << 16);
    if ((gu & 1) == 0) {
      unsigned int* cnxt = (unsigned int*)chain_ptr(Zx, hbuf1, chainD, t + 1);
      __hip_atomic_store(&cnxt[rglob * 512 + w * 2 + (gu >> 1)], hpack,
                         __ATOMIC_RELAXED, __HIP_MEMORY_SCOPE_AGENT);
    }

    // Drain own sc1 stores to LLC, then publish flag (sc1 store).
    COMPILER_FENCE();
    WAIT_VM0();
    COMPILER_FENCE();
    __syncthreads();
    if (tid == 0)
      __hip_atomic_store(&flags[w * 16], t + 2, __ATOMIC_RELAXED, __HIP_MEMORY_SCOPE_AGENT);
  }
}

// ---------------------------------------------------------------- k4
// Reads decoder h directly from chainD: buffer td = h after step 256+td.
__global__ __launch_bounds__(256, 1)
void k4_proj(const unsigned short* __restrict__ hs,   // = chainD
             const unsigned short* __restrict__ WT,   // WprojT [64][1024]
             const float* __restrict__ b_proj,
             float* __restrict__ out)
{
  __shared__ __align__(16) unsigned short Wl[64 * 264];
  __shared__ float zb[4 * 16 * 68];
  const int tid = threadIdx.x;
  const int wv = tid >> 6, lane = tid & 63;
  const int q = lane >> 4, m = lane & 15;
  const int row0 = blockIdx.x * 64 + wv * 16;
  f32x4 acc[4];
#pragma unroll
  for (int nt = 0; nt < 4; ++nt) acc[nt] = (f32x4){0.f, 0.f, 0.f, 0.f};

  for (int kp = 0; kp < 4; ++kp) {
    __syncthreads();
    for (int i = tid; i < 64 * 32; i += 256) {
      const int n = i >> 5, kc = i & 31;
      *(short8*)(&Wl[n * 264 + kc * 8]) =
          *(const short8*)(WT + (size_t)n * 1024 + kp * 256 + kc * 8);
    }
    __syncthreads();
    const unsigned short* aptr = hs + (size_t)(row0 + m) * 1024 + kp * 256 + q * 8;
#pragma unroll 2
    for (int kt = 0; kt < 8; ++kt) {
      const short8 af = *(const short8*)(aptr + kt * 32);
#pragma unroll
      for (int nt = 0; nt < 4; ++nt) {
        const short8 bfr = *(const short8*)(&Wl[(nt * 16 + m) * 264 + kt * 32 + q * 8]);
        acc[nt] = MFMA16(af, bfr, acc[nt]);
      }
    }
  }
  float* z = &zb[wv * (16 * 68)];
#pragma unroll
  for (int nt = 0; nt < 4; ++nt)
#pragma unroll
    for (int i = 0; i < 4; ++i)
      z[(q * 4 + i) * 68 + nt * 16 + m] = acc[nt][i];
  __syncthreads();
  const int r = lane >> 2, s = lane & 3;
  const float* zrow = z + r * 68 + s * 16;
  float v[16];
  float mx = -1e30f;
#pragma unroll
  for (int j = 0; j < 16; ++j) {
    v[j] = zrow[j] + b_proj[s * 16 + j];
    mx = fmaxf(mx, v[j]);
  }
  mx = fmaxf(mx, __shfl_xor(mx, 1));
  mx = fmaxf(mx, __shfl_xor(mx, 2));
  float sum = 0.f;
#pragma unroll
  for (int j = 0; j < 16; ++j) { v[j] = __expf(v[j] - mx); sum += v[j]; }
  sum += __shfl_xor(sum, 1);
  sum += __shfl_xor(sum, 2);
  const float inv = 1.0f / sum;
  const int nrow = row0 + r;
  const int b = nrow & 63, t = nrow >> 6;
  float* op = out + ((size_t)b * 256 + t) * 64 + s * 16;
#pragma unroll
  for (int x = 0; x < 4; ++x) {
    const float4v o4 = { v[4 * x] * inv, v[4 * x + 1] * inv,
                         v[4 * x + 2] * inv, v[4 * x + 3] * inv };
    *(float4v*)(op + 4 * x) = o4;
  }
}

// ---------------------------------------------------------------- launch
extern "C" void kernel_launch(void* const* d_in, const int* in_sizes, int n_in,
                              void* d_out, int out_size, void* d_ws, size_t ws_size,
                              hipStream_t stream)
{
  const int*   tok_src = (const int*)d_in[0];
  const int*   tok_tgt = (const int*)d_in[1];
  const float* emb_src = (const float*)d_in[2];
  const float* emb_tgt = (const float*)d_in[3];
  const float* W_lstm  = (const float*)d_in[4];
  const float* b_lstm  = (const float*)d_in[5];
  const float* W_proj  = (const float*)d_in[6];
  const float* b_proj  = (const float*)d_in[7];
  float* out = (float*)d_out;

  char* ws = (char*)d_ws;
  size_t off = 0;
  int* flags            = (int*)(ws + off);            off += 16384;  // 256 x 64B
  unsigned short* A     = (unsigned short*)(ws + off); off += (size_t)16512 * 512 * 2;
  unsigned short* WT    = (unsigned short*)(ws + off); off += (size_t)4096 * 1536 * 2;
  unsigned short* WPT   = (unsigned short*)(ws + off); off += (size_t)64 * 1024 * 2;
  unsigned short* Zx    = (unsigned short*)(ws + off); off += (size_t)16512 * 4096 * 2;
  unsigned short* hbuf1 = (unsigned short*)(ws + off); off += (size_t)64 * 1024 * 2;
  unsigned short* chainD= (unsigned short*)(ws + off); off += (size_t)256 * 64 * 1024 * 2;
  if (ws_size < off) return;  // insufficient workspace -> loud correctness failure

  hipMemsetAsync(flags, 0, 16384, stream);
  hipLaunchKernelGGL(k1a_gather, dim3(16512), dim3(128), 0, stream, tok_src, emb_src, emb_tgt, A);
  hipLaunchKernelGGL(k1w_perm,   dim3(3072),  dim3(256), 0, stream, W_lstm, WT);
  hipLaunchKernelGGL(k1p_perm,   dim3(32),    dim3(256), 0, stream, W_proj, WPT);
  hipLaunchKernelGGL(k2_gemm,    dim3(32, 129), dim3(256), 0, stream, A, WT, Zx);
  hipLaunchKernelGGL(k3_rnn,     dim3(256),   dim3(256), 0, stream, Zx, WT, b_lstm, tok_tgt, hbuf1, chainD, flags);
  hipLaunchKernelGGL(k4_proj,    dim3(256),   dim3(256), 0, stream, chainD, WPT, b_proj, out);
}

// Round 5
// 4655.922 us; speedup vs baseline: 2.5965x; 1.0124x over previous
//
#include <hip/hip_runtime.h>

// Seq2seq LSTM (B=64, T=256, E=512, H=1024, V_TGT=64) on gfx950.
//   k1a: gather+convert A_bf16[16512][512]
//   k1w: W_lstm fp32 [1536][4096] -> WpermT bf16 [4096][1536] (col-permuted)
//   k1p: W_proj -> WprojT bf16 [64][1024]
//   k2 : Zx bf16 [16512][4096] = A @ Wx
//   k3 : persistent 256-WG recurrence.
//        - h flows through 512 WRITE-ONCE buffers: producers sc1-store (LLC),
//          consumers use PLAIN 16B loads -> per-XCD L2 sharing.
//        - W_h slice in VGPRs (128/wave) -> zero per-step ds_reads.
//        - Round-5: centralized counting barrier. Round-4's per-WG flag array
//          was polled by EVERY thread at 64B stride -> ~65k LLC lines per poll
//          round (LLC DoS, ~6 us/step of the 8.7). Now: one atomicAdd per WG
//          per step into cnt[t+1], single-lane poll of the single cnt[t] line.
//   k4 : projection + softmax -> d_out fp32 [64][256][64]

typedef __attribute__((ext_vector_type(8))) short short8;        // bf16 frag
typedef __attribute__((ext_vector_type(4))) float f32x4;         // MFMA acc
typedef __attribute__((ext_vector_type(4))) float float4v;
typedef __attribute__((ext_vector_type(4))) unsigned short ushort4v;

#define MFMA16(A, B, C) __builtin_amdgcn_mfma_f32_16x16x32_bf16((A), (B), (C), 0, 0, 0)
#define WAIT_VM0() __builtin_amdgcn_s_waitcnt(0x0F70)   // vmcnt(0), ignore exp/lgkm
#define COMPILER_FENCE() asm volatile("" ::: "memory")

__device__ __forceinline__ unsigned short f2bf(float f) {
  union { float f; unsigned u; } v; v.f = f;
  unsigned r = (v.u + 0x7fffu + ((v.u >> 16) & 1u)) >> 16;   // RNE, no NaN in data
  return (unsigned short)r;
}
__device__ __forceinline__ float bf2f(unsigned short h) {
  union { unsigned u; float f; } v; v.u = ((unsigned)h) << 16;
  return v.f;
}
__device__ __forceinline__ float sigf(float x) { return 1.0f / (1.0f + __expf(-x)); }
__device__ __forceinline__ float tanhf_fast(float x) { return 1.0f - 2.0f / (1.0f + __expf(2.0f * x)); }

// Chain buffer C_t (h-state consumed at step t), t in 1..512.
//   t==1      : dedicated hbuf1 (128 KB)
//   2..256    : overlay dead Zx encoder region (t-2): byte off (t-2)*512KB
//   257..512  : dedicated decoder chain (also k4's input), 128 KB each
__device__ __forceinline__ unsigned short*
chain_ptr(unsigned short* Zx, unsigned short* hbuf1, unsigned short* chainD, int t)
{
  if (t == 1)  return hbuf1;
  if (t < 257) return Zx + (size_t)(t - 2) * 262144;
  return chainD + (size_t)(t - 257) * 65536;
}

// ---------------------------------------------------------------- k1a
__global__ __launch_bounds__(128)
void k1a_gather(const int* __restrict__ tok_src,
                const float* __restrict__ emb_src,
                const float* __restrict__ emb_tgt,
                unsigned short* __restrict__ A)
{
  const int n = blockIdx.x;     // 0..16511
  const int i = threadIdx.x;    // 0..127, each does 4 elements
  float4v v = {0.f, 0.f, 0.f, 0.f};
  if (n < 16384) {
    const int b = n & 63, t = n >> 6;                 // row n = t*64 + b
    const int tk = tok_src[b * 256 + t];              // input_source[b][t]
    v = *(const float4v*)(emb_src + (size_t)tk * 512 + i * 4);
  } else if (n < 16448) {
    v = *(const float4v*)(emb_tgt + (size_t)(n - 16384) * 512 + i * 4);
  }
  ushort4v o;
  o.x = f2bf(v.x); o.y = f2bf(v.y); o.z = f2bf(v.z); o.w = f2bf(v.w);
  *(ushort4v*)(A + (size_t)n * 512 + i * 4) = o;
}

// ---------------------------------------------------------------- k1w
__global__ __launch_bounds__(256)
void k1w_perm(const float* __restrict__ W, unsigned short* __restrict__ WT)
{
  const int id = blockIdx.x * 256 + threadIdx.x;  // < 786432 = 4096 * 192
  const int n  = id & 4095;                        // permuted col
  const int k0 = (id >> 12) * 8;                   // 0..1528
  const int g = n & 3, u = (n >> 2) & 3, wq = n >> 4;
  const int oc = g * 1024 + 4 * wq + u;
  short8 o;
#pragma unroll
  for (int j = 0; j < 8; ++j)
    o[j] = (short)f2bf(W[(size_t)(k0 + j) * 4096 + oc]);
  *(short8*)(WT + (size_t)n * 1536 + k0) = o;
}

// ---------------------------------------------------------------- k1p
__global__ __launch_bounds__(256)
void k1p_perm(const float* __restrict__ W, unsigned short* __restrict__ WT)
{
  const int id = blockIdx.x * 256 + threadIdx.x;  // < 8192 = 64 * 128
  const int n  = id & 63;
  const int k0 = (id >> 6) * 8;
  short8 o;
#pragma unroll
  for (int j = 0; j < 8; ++j)
    o[j] = (short)f2bf(W[(size_t)(k0 + j) * 64 + n]);
  *(short8*)(WT + (size_t)n * 1024 + k0) = o;
}

// ---------------------------------------------------------------- k2
__global__ __launch_bounds__(256, 1)
void k2_gemm(const unsigned short* __restrict__ A,
             const unsigned short* __restrict__ BT,
             unsigned short* __restrict__ C)
{
  __shared__ __align__(16) unsigned short As[128 * 40];
  __shared__ __align__(16) unsigned short Bs[128 * 40];
  const int tid = threadIdx.x;
  const int n0 = blockIdx.x * 128;   // 32 blocks
  const int m0 = blockIdx.y * 128;   // 129 blocks
  const int wv = tid >> 6, lane = tid & 63;
  const int wr = wv & 1, wc = wv >> 1;
  const int q = lane >> 4, l15 = lane & 15;
  f32x4 acc[4][4];
#pragma unroll
  for (int a = 0; a < 4; ++a)
#pragma unroll
    for (int b = 0; b < 4; ++b)
      acc[a][b] = (f32x4){0.f, 0.f, 0.f, 0.f};

  for (int kt = 0; kt < 16; ++kt) {   // K = 512, BK = 32
    __syncthreads();
#pragma unroll
    for (int s = 0; s < 2; ++s) {
      const int ci = tid + s * 256;
      const int row = ci >> 2, kc = ci & 3;
      *(short8*)(&As[row * 40 + kc * 8]) =
          *(const short8*)(A + (size_t)(m0 + row) * 512 + kt * 32 + kc * 8);
      *(short8*)(&Bs[row * 40 + kc * 8]) =
          *(const short8*)(BT + (size_t)(n0 + row) * 1536 + kt * 32 + kc * 8);
    }
    __syncthreads();
    short8 af[4], bf[4];
#pragma unroll
    for (int i = 0; i < 4; ++i) {
      af[i] = *(const short8*)(&As[(wr * 64 + i * 16 + l15) * 40 + q * 8]);
      bf[i] = *(const short8*)(&Bs[(wc * 64 + i * 16 + l15) * 40 + q * 8]);
    }
#pragma unroll
    for (int mi = 0; mi < 4; ++mi)
#pragma unroll
      for (int ni = 0; ni < 4; ++ni)
        acc[mi][ni] = MFMA16(af[mi], bf[ni], acc[mi][ni]);
  }
#pragma unroll
  for (int mi = 0; mi < 4; ++mi)
#pragma unroll
    for (int ni = 0; ni < 4; ++ni)
#pragma unroll
      for (int i = 0; i < 4; ++i) {
        const int row = m0 + wr * 64 + mi * 16 + q * 4 + i;
        const int col = n0 + wc * 64 + ni * 16 + l15;
        C[(size_t)row * 4096 + col] = f2bf(acc[mi][ni][i]);
      }
}

// ---------------------------------------------------------------- k3
// 256 WGs x 256 threads, 512 steps. WG w owns hidden units 4w..4w+3.
__global__ __launch_bounds__(256, 1)
void k3_rnn(unsigned short* __restrict__ Zx,
            const unsigned short* __restrict__ WT,
            const float* __restrict__ b_lstm,
            const int* __restrict__ tok_tgt,
            unsigned short* __restrict__ hbuf1,    // C_1 (128 KB)
            unsigned short* __restrict__ chainD,   // C_257..C_512 (32 MB)
            int* __restrict__ cnt)                 // [513] per-step arrival counters
{
  __shared__ float ztile[4 * 16 * 17];             // per-wave 16x16 (+1 pad)
  __shared__ int s_dead;
  const int w = blockIdx.x;
  const int tid = threadIdx.x;
  const int wv = tid >> 6, lane = tid & 63;

  // Gate-phase lane mapping: 64 lanes = 16 rows x 4 units.
  const int gr = lane >> 2, gu = lane & 3;
  const int rglob = wv * 16 + gr;
  const float bias0 = b_lstm[4 * w + gu];                  // i
  const float bias1 = b_lstm[1024 + 4 * w + gu];           // j
  const float bias2 = b_lstm[2048 + 4 * w + gu] + 1.0f;    // f + forget_bias
  const float bias3 = b_lstm[3072 + 4 * w + gu];           // o
  float cst = 0.f;
  // MFMA-phase lane mapping.
  const int q = lane >> 4, m15 = lane & 15;
  const int arow = wv * 16 + m15;
  float* const zt_w = &ztile[wv * 272];

  // Preload the wave's W_h B-frags into VGPRs: col w*16+m15, k 512+kt*32+q*8.
  short8 Breg[32];
  {
    const unsigned short* wsrc = WT + (size_t)(w * 16 + m15) * 1536 + 512 + q * 8;
#pragma unroll
    for (int kt = 0; kt < 32; ++kt)
      Breg[kt] = *(const short8*)(wsrc + kt * 32);
  }
  if (tid == 0) s_dead = 0;
  __syncthreads();

  for (int t = 0; t < 512; ++t) {
    // Prefetch x-contribution (overlaps the barrier wait).
    unsigned long long zx8;
    if (t < 256) {
      // Encoder Zx rows: sc1 (L1/L2-bypass) so overlaid chain reads stay safe.
      const size_t xrow = (size_t)(t * 64 + rglob);
      zx8 = __hip_atomic_load((const unsigned long long*)(Zx + xrow * 4096 + w * 16 + gu * 4),
                              __ATOMIC_RELAXED, __HIP_MEMORY_SCOPE_AGENT);
    } else {
      // Decoder table rows 16384+tok: never overlaid -> normal (L2-hot) load.
      const size_t xrow = (size_t)(16384 + tok_tgt[rglob * 256 + (t - 256)]);
      zx8 = *(const unsigned long long*)(Zx + xrow * 4096 + w * 16 + gu * 4);
    }

    // Barrier-in: C_t fully published <=> cnt[t] == 256. Single-lane poll of
    // a single line (round-4's all-thread 64B-stride poll was an LLC DoS).
    if (t > 0) {
      if (tid == 0) {
        int spin = 0;
        while (__hip_atomic_load(&cnt[t], __ATOMIC_RELAXED, __HIP_MEMORY_SCOPE_AGENT) < 256) {
          __builtin_amdgcn_s_sleep(1);
          if (++spin > (1 << 18)) { s_dead = 1; break; }   // ~80 ms escape hatch
        }
      }
      COMPILER_FENCE();
      __syncthreads();
      if (s_dead) break;
    }

    // z_tile = h[16 rows][1024] @ Wh_slice[1024][16]; h via plain 16B loads
    // (write-once buffer: correct value is the only value these lines can hold).
    f32x4 acc0 = {0.f, 0.f, 0.f, 0.f};
    f32x4 acc1 = {0.f, 0.f, 0.f, 0.f};
    f32x4 acc2 = {0.f, 0.f, 0.f, 0.f};
    f32x4 acc3 = {0.f, 0.f, 0.f, 0.f};
    if (t > 0) {
      const unsigned short* hb = chain_ptr(Zx, hbuf1, chainD, t);
      const unsigned short* ap = hb + arow * 1024 + q * 8;
#pragma unroll
      for (int kt = 0; kt < 8; ++kt) {
        const short8 a0 = *(const short8*)(ap + kt * 32);
        const short8 a1 = *(const short8*)(ap + (kt + 8) * 32);
        const short8 a2 = *(const short8*)(ap + (kt + 16) * 32);
        const short8 a3 = *(const short8*)(ap + (kt + 24) * 32);
        acc0 = MFMA16(a0, Breg[kt], acc0);
        acc1 = MFMA16(a1, Breg[kt + 8], acc1);
        acc2 = MFMA16(a2, Breg[kt + 16], acc2);
        acc3 = MFMA16(a3, Breg[kt + 24], acc3);
      }
    }
    // Transpose through wave-private LDS: C-layout -> (row, unit) lanes.
#pragma unroll
    for (int i = 0; i < 4; ++i)
      zt_w[(q * 4 + i) * 17 + m15] = (acc0[i] + acc1[i]) + (acc2[i] + acc3[i]);
    __builtin_amdgcn_s_waitcnt(0xC07F);   // lgkmcnt(0)
    const float* zr = zt_w + gr * 17 + gu * 4;
    float z0 = zr[0], z1 = zr[1], z2 = zr[2], z3 = zr[3];

    z0 += bf2f((unsigned short)(zx8 >> 0))  + bias0;
    z1 += bf2f((unsigned short)(zx8 >> 16)) + bias1;
    z2 += bf2f((unsigned short)(zx8 >> 32)) + bias2;
    z3 += bf2f((unsigned short)(zx8 >> 48)) + bias3;

    const float ig = sigf(z0);
    const float jg = tanhf_fast(z1);
    const float fg = sigf(z2);
    const float og = sigf(z3);
    cst = fg * cst + ig * jg;
    const float hv = og * tanhf_fast(cst);
    const unsigned short hb16 = f2bf(hv);

    // Pack two adjacent units into one dword; lanes gu=0,2 sc1-store to C_{t+1}.
    const unsigned int partner = (unsigned int)(unsigned short)__shfl_down((int)hb16, 1);
    const unsigned int hpack = (unsigned int)hb16 | (partner << 16);
    if ((gu & 1) == 0) {
      unsigned int* cnxt = (unsigned int*)chain_ptr(Zx, hbuf1, chainD, t + 1);
      __hip_atomic_store(&cnxt[rglob * 512 + w * 2 + (gu >> 1)], hpack,
                         __ATOMIC_RELAXED, __HIP_MEMORY_SCOPE_AGENT);
    }

    // Drain own sc1 stores to LLC, then publish arrival (one atomicAdd per WG).
    COMPILER_FENCE();
    WAIT_VM0();
    COMPILER_FENCE();
    __syncthreads();
    if (tid == 0)
      __hip_atomic_fetch_add(&cnt[t + 1], 1, __ATOMIC_RELAXED, __HIP_MEMORY_SCOPE_AGENT);
  }
}

// ---------------------------------------------------------------- k4
// Reads decoder h directly from chainD: buffer td = h after step 256+td.
__global__ __launch_bounds__(256, 1)
void k4_proj(const unsigned short* __restrict__ hs,   // = chainD
             const unsigned short* __restrict__ WT,   // WprojT [64][1024]
             const float* __restrict__ b_proj,
             float* __restrict__ out)
{
  __shared__ __align__(16) unsigned short Wl[64 * 264];
  __shared__ float zb[4 * 16 * 68];
  const int tid = threadIdx.x;
  const int wv = tid >> 6, lane = tid & 63;
  const int q = lane >> 4, m = lane & 15;
  const int row0 = blockIdx.x * 64 + wv * 16;
  f32x4 acc[4];
#pragma unroll
  for (int nt = 0; nt < 4; ++nt) acc[nt] = (f32x4){0.f, 0.f, 0.f, 0.f};

  for (int kp = 0; kp < 4; ++kp) {
    __syncthreads();
    for (int i = tid; i < 64 * 32; i += 256) {
      const int n = i >> 5, kc = i & 31;
      *(short8*)(&Wl[n * 264 + kc * 8]) =
          *(const short8*)(WT + (size_t)n * 1024 + kp * 256 + kc * 8);
    }
    __syncthreads();
    const unsigned short* aptr = hs + (size_t)(row0 + m) * 1024 + kp * 256 + q * 8;
#pragma unroll 2
    for (int kt = 0; kt < 8; ++kt) {
      const short8 af = *(const short8*)(aptr + kt * 32);
#pragma unroll
      for (int nt = 0; nt < 4; ++nt) {
        const short8 bfr = *(const short8*)(&Wl[(nt * 16 + m) * 264 + kt * 32 + q * 8]);
        acc[nt] = MFMA16(af, bfr, acc[nt]);
      }
    }
  }
  float* z = &zb[wv * (16 * 68)];
#pragma unroll
  for (int nt = 0; nt < 4; ++nt)
#pragma unroll
    for (int i = 0; i < 4; ++i)
      z[(q * 4 + i) * 68 + nt * 16 + m] = acc[nt][i];
  __syncthreads();
  const int r = lane >> 2, s = lane & 3;
  const float* zrow = z + r * 68 + s * 16;
  float v[16];
  float mx = -1e30f;
#pragma unroll
  for (int j = 0; j < 16; ++j) {
    v[j] = zrow[j] + b_proj[s * 16 + j];
    mx = fmaxf(mx, v[j]);
  }
  mx = fmaxf(mx, __shfl_xor(mx, 1));
  mx = fmaxf(mx, __shfl_xor(mx, 2));
  float sum = 0.f;
#pragma unroll
  for (int j = 0; j < 16; ++j) { v[j] = __expf(v[j] - mx); sum += v[j]; }
  sum += __shfl_xor(sum, 1);
  sum += __shfl_xor(sum, 2);
  const float inv = 1.0f / sum;
  const int nrow = row0 + r;
  const int b = nrow & 63, t = nrow >> 6;
  float* op = out + ((size_t)b * 256 + t) * 64 + s * 16;
#pragma unroll
  for (int x = 0; x < 4; ++x) {
    const float4v o4 = { v[4 * x] * inv, v[4 * x + 1] * inv,
                         v[4 * x + 2] * inv, v[4 * x + 3] * inv };
    *(float4v*)(op + 4 * x) = o4;
  }
}

// ---------------------------------------------------------------- launch
extern "C" void kernel_launch(void* const* d_in, const int* in_sizes, int n_in,
                              void* d_out, int out_size, void* d_ws, size_t ws_size,
                              hipStream_t stream)
{
  const int*   tok_src = (const int*)d_in[0];
  const int*   tok_tgt = (const int*)d_in[1];
  const float* emb_src = (const float*)d_in[2];
  const float* emb_tgt = (const float*)d_in[3];
  const float* W_lstm  = (const float*)d_in[4];
  const float* b_lstm  = (const float*)d_in[5];
  const float* W_proj  = (const float*)d_in[6];
  const float* b_proj  = (const float*)d_in[7];
  float* out = (float*)d_out;

  char* ws = (char*)d_ws;
  size_t off = 0;
  int* cnt              = (int*)(ws + off);            off += 16384;  // 513 used
  unsigned short* A     = (unsigned short*)(ws + off); off += (size_t)16512 * 512 * 2;
  unsigned short* WT    = (unsigned short*)(ws + off); off += (size_t)4096 * 1536 * 2;
  unsigned short* WPT   = (unsigned short*)(ws + off); off += (size_t)64 * 1024 * 2;
  unsigned short* Zx    = (unsigned short*)(ws + off); off += (size_t)16512 * 4096 * 2;
  unsigned short* hbuf1 = (unsigned short*)(ws + off); off += (size_t)64 * 1024 * 2;
  unsigned short* chainD= (unsigned short*)(ws + off); off += (size_t)256 * 64 * 1024 * 2;
  if (ws_size < off) return;  // insufficient workspace -> loud correctness failure

  hipMemsetAsync(cnt, 0, 16384, stream);
  hipLaunchKernelGGL(k1a_gather, dim3(16512), dim3(128), 0, stream, tok_src, emb_src, emb_tgt, A);
  hipLaunchKernelGGL(k1w_perm,   dim3(3072),  dim3(256), 0, stream, W_lstm, WT);
  hipLaunchKernelGGL(k1p_perm,   dim3(32),    dim3(256), 0, stream, W_proj, WPT);
  hipLaunchKernelGGL(k2_gemm,    dim3(32, 129), dim3(256), 0, stream, A, WT, Zx);
  hipLaunchKernelGGL(k3_rnn,     dim3(256),   dim3(256), 0, stream, Zx, WT, b_lstm, tok_tgt, hbuf1, chainD, cnt);
  hipLaunchKernelGGL(k4_proj,    dim3(256),   dim3(256), 0, stream, chainD, WPT, b_proj, out);
}

// Round 6
// 3369.184 us; speedup vs baseline: 3.5881x; 1.3819x over previous
//
#include <hip/hip_runtime.h>

// Seq2seq LSTM (B=64, T=256, E=512, H=1024, V_TGT=64) on gfx950.
//   k1a: gather+convert A_bf16[16512][512]
//   k1w: W_lstm fp32 [1536][4096] -> WpermT bf16 [4096][1536] (col-permuted)
//   k1p: W_proj -> WprojT bf16 [64][1024]
//   k2 : Zx bf16 [16512][4096] = A @ Wx
//   k3 : persistent 256-WG recurrence.
//        - h flows through 512 WRITE-ONCE buffers: producers sc1-store (LLC),
//          consumers use PLAIN 16B loads -> per-XCD L2 sharing.
//        - W_h slice in VGPRs -> zero per-step ds_reads.
//        - Round-6: contention-isolated tournament barrier. r3/r4/r5 all put
//          the publish write on a line saturated by poll reads (r5: cnt[t] and
//          cnt[t+1] share one 128B line: 256-WG poll storm + 256 RMWs on the
//          same line ~ 256x80cy = 8.5us = the whole step time). Now: arrival
//          RMW lines have zero pollers (8 lines x 32 adds, read only by WG0);
//          release go-lines have one write + <=32 pollers each.
//        - Round-6b: 2D partition (WG = 16 batch rows x 16 units): the 4 waves
//          of a WG read the SAME 16 h-rows -> 32KB/CU/step (was 128KB), L1
//          broadcast + 4x less L2 read pressure.
//   k4 : projection + softmax -> d_out fp32 [64][256][64]

typedef __attribute__((ext_vector_type(8))) short short8;        // bf16 frag
typedef __attribute__((ext_vector_type(4))) float f32x4;         // MFMA acc
typedef __attribute__((ext_vector_type(4))) float float4v;
typedef __attribute__((ext_vector_type(4))) unsigned short ushort4v;

#define MFMA16(A, B, C) __builtin_amdgcn_mfma_f32_16x16x32_bf16((A), (B), (C), 0, 0, 0)
#define WAIT_VM0() __builtin_amdgcn_s_waitcnt(0x0F70)   // vmcnt(0), ignore exp/lgkm
#define COMPILER_FENCE() asm volatile("" ::: "memory")

__device__ __forceinline__ unsigned short f2bf(float f) {
  union { float f; unsigned u; } v; v.f = f;
  unsigned r = (v.u + 0x7fffu + ((v.u >> 16) & 1u)) >> 16;   // RNE, no NaN in data
  return (unsigned short)r;
}
__device__ __forceinline__ float bf2f(unsigned short h) {
  union { unsigned u; float f; } v; v.u = ((unsigned)h) << 16;
  return v.f;
}
__device__ __forceinline__ float sigf(float x) { return 1.0f / (1.0f + __expf(-x)); }
__device__ __forceinline__ float tanhf_fast(float x) { return 1.0f - 2.0f / (1.0f + __expf(2.0f * x)); }

// Chain buffer C_t (h-state consumed at step t), t in 1..512.
//   t==1      : dedicated hbuf1 (128 KB)
//   2..256    : overlay dead Zx encoder region (t-2): byte off (t-2)*512KB
//   257..512  : dedicated decoder chain (also k4's input), 128 KB each
__device__ __forceinline__ unsigned short*
chain_ptr(unsigned short* Zx, unsigned short* hbuf1, unsigned short* chainD, int t)
{
  if (t == 1)  return hbuf1;
  if (t < 257) return Zx + (size_t)(t - 2) * 262144;
  return chainD + (size_t)(t - 257) * 65536;
}

// ---------------------------------------------------------------- k1a
__global__ __launch_bounds__(128)
void k1a_gather(const int* __restrict__ tok_src,
                const float* __restrict__ emb_src,
                const float* __restrict__ emb_tgt,
                unsigned short* __restrict__ A)
{
  const int n = blockIdx.x;     // 0..16511
  const int i = threadIdx.x;    // 0..127, each does 4 elements
  float4v v = {0.f, 0.f, 0.f, 0.f};
  if (n < 16384) {
    const int b = n & 63, t = n >> 6;                 // row n = t*64 + b
    const int tk = tok_src[b * 256 + t];              // input_source[b][t]
    v = *(const float4v*)(emb_src + (size_t)tk * 512 + i * 4);
  } else if (n < 16448) {
    v = *(const float4v*)(emb_tgt + (size_t)(n - 16384) * 512 + i * 4);
  }
  ushort4v o;
  o.x = f2bf(v.x); o.y = f2bf(v.y); o.z = f2bf(v.z); o.w = f2bf(v.w);
  *(ushort4v*)(A + (size_t)n * 512 + i * 4) = o;
}

// ---------------------------------------------------------------- k1w
__global__ __launch_bounds__(256)
void k1w_perm(const float* __restrict__ W, unsigned short* __restrict__ WT)
{
  const int id = blockIdx.x * 256 + threadIdx.x;  // < 786432 = 4096 * 192
  const int n  = id & 4095;                        // permuted col
  const int k0 = (id >> 12) * 8;                   // 0..1528
  const int g = n & 3, u = (n >> 2) & 3, wq = n >> 4;
  const int oc = g * 1024 + 4 * wq + u;
  short8 o;
#pragma unroll
  for (int j = 0; j < 8; ++j)
    o[j] = (short)f2bf(W[(size_t)(k0 + j) * 4096 + oc]);
  *(short8*)(WT + (size_t)n * 1536 + k0) = o;
}

// ---------------------------------------------------------------- k1p
__global__ __launch_bounds__(256)
void k1p_perm(const float* __restrict__ W, unsigned short* __restrict__ WT)
{
  const int id = blockIdx.x * 256 + threadIdx.x;  // < 8192 = 64 * 128
  const int n  = id & 63;
  const int k0 = (id >> 6) * 8;
  short8 o;
#pragma unroll
  for (int j = 0; j < 8; ++j)
    o[j] = (short)f2bf(W[(size_t)(k0 + j) * 64 + n]);
  *(short8*)(WT + (size_t)n * 1024 + k0) = o;
}

// ---------------------------------------------------------------- k2
__global__ __launch_bounds__(256, 1)
void k2_gemm(const unsigned short* __restrict__ A,
             const unsigned short* __restrict__ BT,
             unsigned short* __restrict__ C)
{
  __shared__ __align__(16) unsigned short As[128 * 40];
  __shared__ __align__(16) unsigned short Bs[128 * 40];
  const int tid = threadIdx.x;
  const int n0 = blockIdx.x * 128;   // 32 blocks
  const int m0 = blockIdx.y * 128;   // 129 blocks
  const int wv = tid >> 6, lane = tid & 63;
  const int wr = wv & 1, wc = wv >> 1;
  const int q = lane >> 4, l15 = lane & 15;
  f32x4 acc[4][4];
#pragma unroll
  for (int a = 0; a < 4; ++a)
#pragma unroll
    for (int b = 0; b < 4; ++b)
      acc[a][b] = (f32x4){0.f, 0.f, 0.f, 0.f};

  for (int kt = 0; kt < 16; ++kt) {   // K = 512, BK = 32
    __syncthreads();
#pragma unroll
    for (int s = 0; s < 2; ++s) {
      const int ci = tid + s * 256;
      const int row = ci >> 2, kc = ci & 3;
      *(short8*)(&As[row * 40 + kc * 8]) =
          *(const short8*)(A + (size_t)(m0 + row) * 512 + kt * 32 + kc * 8);
      *(short8*)(&Bs[row * 40 + kc * 8]) =
          *(const short8*)(BT + (size_t)(n0 + row) * 1536 + kt * 32 + kc * 8);
    }
    __syncthreads();
    short8 af[4], bf[4];
#pragma unroll
    for (int i = 0; i < 4; ++i) {
      af[i] = *(const short8*)(&As[(wr * 64 + i * 16 + l15) * 40 + q * 8]);
      bf[i] = *(const short8*)(&Bs[(wc * 64 + i * 16 + l15) * 40 + q * 8]);
    }
#pragma unroll
    for (int mi = 0; mi < 4; ++mi)
#pragma unroll
      for (int ni = 0; ni < 4; ++ni)
        acc[mi][ni] = MFMA16(af[mi], bf[ni], acc[mi][ni]);
  }
#pragma unroll
  for (int mi = 0; mi < 4; ++mi)
#pragma unroll
    for (int ni = 0; ni < 4; ++ni)
#pragma unroll
      for (int i = 0; i < 4; ++i) {
        const int row = m0 + wr * 64 + mi * 16 + q * 4 + i;
        const int col = n0 + wc * 64 + ni * 16 + l15;
        C[(size_t)row * 4096 + col] = f2bf(acc[mi][ni][i]);
      }
}

// ---------------------------------------------------------------- k3
// 256 WGs x 256 threads, 512 steps.
// WG w: batch rows 16*(w&3)..+15, units 16*(w>>2)..+15; wave v -> unit-quad
// Q = 4*(w>>2)+v (16 permuted gate cols). All 4 waves read the same 16 h-rows.
__global__ __launch_bounds__(256, 1)
void k3_rnn(unsigned short* __restrict__ Zx,
            const unsigned short* __restrict__ WT,
            const float* __restrict__ b_lstm,
            const int* __restrict__ tok_tgt,
            unsigned short* __restrict__ hbuf1,    // C_1 (128 KB)
            unsigned short* __restrict__ chainD,   // C_257..C_512 (32 MB)
            int* __restrict__ arr,                 // [513][8] arrival cnt, 128B lines
            int* __restrict__ go)                  // [513][8] release flags, 128B lines
{
  __shared__ float ztile[4 * 16 * 17];             // per-wave 16x16 (+1 pad)
  __shared__ int s_dead;
  const int w = blockIdx.x;
  const int tid = threadIdx.x;
  const int wv = tid >> 6, lane = tid & 63;
  const int bg = w & 3;            // batch group
  const int ug = w >> 2;           // unit group
  const int Q  = 4 * ug + wv;      // this wave's unit-quad (0..255)
  const int rbase = bg * 16;
  const int grp = w >> 5;          // barrier group 0..7

  // Gate-phase lane mapping: 64 lanes = 16 rows x 4 units.
  const int gr = lane >> 2, gu = lane & 3;
  const int rglob = rbase + gr;
  const float bias0 = b_lstm[4 * Q + gu];                  // i
  const float bias1 = b_lstm[1024 + 4 * Q + gu];           // j
  const float bias2 = b_lstm[2048 + 4 * Q + gu] + 1.0f;    // f + forget_bias
  const float bias3 = b_lstm[3072 + 4 * Q + gu];           // o
  float cst = 0.f;
  // MFMA-phase lane mapping.
  const int q = lane >> 4, m15 = lane & 15;
  const int arow = rbase + m15;
  float* const zt_w = &ztile[wv * 272];

  // Preload the wave's W_h B-frags into VGPRs: col Q*16+m15, k 512+kt*32+q*8.
  short8 Breg[32];
  {
    const unsigned short* wsrc = WT + (size_t)(Q * 16 + m15) * 1536 + 512 + q * 8;
#pragma unroll
    for (int kt = 0; kt < 32; ++kt)
      Breg[kt] = *(const short8*)(wsrc + kt * 32);
  }
  if (tid == 0) s_dead = 0;
  __syncthreads();

  for (int t = 0; t < 512; ++t) {
    // Prefetch x-contribution (overlaps the barrier wait).
    unsigned long long zx8;
    if (t < 256) {
      // Encoder Zx rows: sc1 (L1/L2-bypass) so overlaid chain reads stay safe.
      const size_t xrow = (size_t)(t * 64 + rglob);
      zx8 = __hip_atomic_load((const unsigned long long*)(Zx + xrow * 4096 + Q * 16 + gu * 4),
                              __ATOMIC_RELAXED, __HIP_MEMORY_SCOPE_AGENT);
    } else {
      // Decoder table rows 16384+tok: never overlaid -> normal (L2-hot) load.
      const size_t xrow = (size_t)(16384 + tok_tgt[rglob * 256 + (t - 256)]);
      zx8 = *(const unsigned long long*)(Zx + xrow * 4096 + Q * 16 + gu * 4);
    }

    // ---- Tournament barrier: wait until C_t fully published. ----
    if (t > 0) {
      if (w == 0) {
        if (wv == 0) {
          int spin = 0;
          for (;;) {
            int v = 32;
            if (lane < 8)
              v = __hip_atomic_load(&arr[(t * 8 + lane) * 32],
                                    __ATOMIC_RELAXED, __HIP_MEMORY_SCOPE_AGENT);
            if (__ballot(v >= 32) == ~0ull) break;
            __builtin_amdgcn_s_sleep(1);
            if (++spin > (1 << 18)) { s_dead = 1; break; }
          }
          if (lane < 8)
            __hip_atomic_store(&go[(t * 8 + lane) * 32], 1,
                               __ATOMIC_RELAXED, __HIP_MEMORY_SCOPE_AGENT);
        }
      } else {
        if (tid == 0) {
          int spin = 0;
          while (__hip_atomic_load(&go[(t * 8 + grp) * 32],
                                   __ATOMIC_RELAXED, __HIP_MEMORY_SCOPE_AGENT) == 0) {
            __builtin_amdgcn_s_sleep(1);
            if (++spin > (1 << 18)) { s_dead = 1; break; }
          }
        }
      }
      COMPILER_FENCE();
      __syncthreads();
      if (s_dead) break;
    }

    // z_tile = h[16 rows][1024] @ Wh_slice[1024][16]; h via plain 16B loads
    // (write-once buffer; all 4 waves read the same rows -> L1 broadcast).
    f32x4 acc0 = {0.f, 0.f, 0.f, 0.f};
    f32x4 acc1 = {0.f, 0.f, 0.f, 0.f};
    f32x4 acc2 = {0.f, 0.f, 0.f, 0.f};
    f32x4 acc3 = {0.f, 0.f, 0.f, 0.f};
    if (t > 0) {
      const unsigned short* hb = chain_ptr(Zx, hbuf1, chainD, t);
      const unsigned short* ap = hb + arow * 1024 + q * 8;
#pragma unroll
      for (int kt = 0; kt < 8; ++kt) {
        const short8 a0 = *(const short8*)(ap + kt * 32);
        const short8 a1 = *(const short8*)(ap + (kt + 8) * 32);
        const short8 a2 = *(const short8*)(ap + (kt + 16) * 32);
        const short8 a3 = *(const short8*)(ap + (kt + 24) * 32);
        acc0 = MFMA16(a0, Breg[kt], acc0);
        acc1 = MFMA16(a1, Breg[kt + 8], acc1);
        acc2 = MFMA16(a2, Breg[kt + 16], acc2);
        acc3 = MFMA16(a3, Breg[kt + 24], acc3);
      }
    }
    // Transpose through wave-private LDS: C-layout -> (row, unit) lanes.
#pragma unroll
    for (int i = 0; i < 4; ++i)
      zt_w[(q * 4 + i) * 17 + m15] = (acc0[i] + acc1[i]) + (acc2[i] + acc3[i]);
    __builtin_amdgcn_s_waitcnt(0xC07F);   // lgkmcnt(0)
    const float* zr = zt_w + gr * 17 + gu * 4;
    float z0 = zr[0], z1 = zr[1], z2 = zr[2], z3 = zr[3];

    z0 += bf2f((unsigned short)(zx8 >> 0))  + bias0;
    z1 += bf2f((unsigned short)(zx8 >> 16)) + bias1;
    z2 += bf2f((unsigned short)(zx8 >> 32)) + bias2;
    z3 += bf2f((unsigned short)(zx8 >> 48)) + bias3;

    const float ig = sigf(z0);
    const float jg = tanhf_fast(z1);
    const float fg = sigf(z2);
    const float og = sigf(z3);
    cst = fg * cst + ig * jg;
    const float hv = og * tanhf_fast(cst);
    const unsigned short hb16 = f2bf(hv);

    // Pack two adjacent units into one dword; lanes gu=0,2 sc1-store to C_{t+1}.
    const unsigned int partner = (unsigned int)(unsigned short)__shfl_down((int)hb16, 1);
    const unsigned int hpack = (unsigned int)hb16 | (partner << 16);
    if ((gu & 1) == 0) {
      unsigned int* cnxt = (unsigned int*)chain_ptr(Zx, hbuf1, chainD, t + 1);
      __hip_atomic_store(&cnxt[rglob * 512 + Q * 2 + (gu >> 1)], hpack,
                         __ATOMIC_RELAXED, __HIP_MEMORY_SCOPE_AGENT);
    }

    // Drain own sc1 stores to LLC, then publish arrival (RMW lines have no
    // pollers; only WG0's lane grp reads them).
    COMPILER_FENCE();
    WAIT_VM0();
    COMPILER_FENCE();
    __syncthreads();
    if (tid == 0)
      __hip_atomic_fetch_add(&arr[((t + 1) * 8 + grp) * 32], 1,
                             __ATOMIC_RELAXED, __HIP_MEMORY_SCOPE_AGENT);
  }
}

// ---------------------------------------------------------------- k4
// Reads decoder h directly from chainD: buffer td = h after step 256+td.
__global__ __launch_bounds__(256, 1)
void k4_proj(const unsigned short* __restrict__ hs,   // = chainD
             const unsigned short* __restrict__ WT,   // WprojT [64][1024]
             const float* __restrict__ b_proj,
             float* __restrict__ out)
{
  __shared__ __align__(16) unsigned short Wl[64 * 264];
  __shared__ float zb[4 * 16 * 68];
  const int tid = threadIdx.x;
  const int wv = tid >> 6, lane = tid & 63;
  const int q = lane >> 4, m = lane & 15;
  const int row0 = blockIdx.x * 64 + wv * 16;
  f32x4 acc[4];
#pragma unroll
  for (int nt = 0; nt < 4; ++nt) acc[nt] = (f32x4){0.f, 0.f, 0.f, 0.f};

  for (int kp = 0; kp < 4; ++kp) {
    __syncthreads();
    for (int i = tid; i < 64 * 32; i += 256) {
      const int n = i >> 5, kc = i & 31;
      *(short8*)(&Wl[n * 264 + kc * 8]) =
          *(const short8*)(WT + (size_t)n * 1024 + kp * 256 + kc * 8);
    }
    __syncthreads();
    const unsigned short* aptr = hs + (size_t)(row0 + m) * 1024 + kp * 256 + q * 8;
#pragma unroll 2
    for (int kt = 0; kt < 8; ++kt) {
      const short8 af = *(const short8*)(aptr + kt * 32);
#pragma unroll
      for (int nt = 0; nt < 4; ++nt) {
        const short8 bfr = *(const short8*)(&Wl[(nt * 16 + m) * 264 + kt * 32 + q * 8]);
        acc[nt] = MFMA16(af, bfr, acc[nt]);
      }
    }
  }
  float* z = &zb[wv * (16 * 68)];
#pragma unroll
  for (int nt = 0; nt < 4; ++nt)
#pragma unroll
    for (int i = 0; i < 4; ++i)
      z[(q * 4 + i) * 68 + nt * 16 + m] = acc[nt][i];
  __syncthreads();
  const int r = lane >> 2, s = lane & 3;
  const float* zrow = z + r * 68 + s * 16;
  float v[16];
  float mx = -1e30f;
#pragma unroll
  for (int j = 0; j < 16; ++j) {
    v[j] = zrow[j] + b_proj[s * 16 + j];
    mx = fmaxf(mx, v[j]);
  }
  mx = fmaxf(mx, __shfl_xor(mx, 1));
  mx = fmaxf(mx, __shfl_xor(mx, 2));
  float sum = 0.f;
#pragma unroll
  for (int j = 0; j < 16; ++j) { v[j] = __expf(v[j] - mx); sum += v[j]; }
  sum += __shfl_xor(sum, 1);
  sum += __shfl_xor(sum, 2);
  const float inv = 1.0f / sum;
  const int nrow = row0 + r;
  const int b = nrow & 63, t = nrow >> 6;
  float* op = out + ((size_t)b * 256 + t) * 64 + s * 16;
#pragma unroll
  for (int x = 0; x < 4; ++x) {
    const float4v o4 = { v[4 * x] * inv, v[4 * x + 1] * inv,
                         v[4 * x + 2] * inv, v[4 * x + 3] * inv };
    *(float4v*)(op + 4 * x) = o4;
  }
}

// ---------------------------------------------------------------- launch
extern "C" void kernel_launch(void* const* d_in, const int* in_sizes, int n_in,
                              void* d_out, int out_size, void* d_ws, size_t ws_size,
                              hipStream_t stream)
{
  const int*   tok_src = (const int*)d_in[0];
  const int*   tok_tgt = (const int*)d_in[1];
  const float* emb_src = (const float*)d_in[2];
  const float* emb_tgt = (const float*)d_in[3];
  const float* W_lstm  = (const float*)d_in[4];
  const float* b_lstm  = (const float*)d_in[5];
  const float* W_proj  = (const float*)d_in[6];
  const float* b_proj  = (const float*)d_in[7];
  float* out = (float*)d_out;

  char* ws = (char*)d_ws;
  size_t off = 0;
  const size_t barrier_bytes = (size_t)513 * 8 * 128;   // 128B line per (t,g)
  int* arr              = (int*)(ws + off);            off += barrier_bytes;
  int* go               = (int*)(ws + off);            off += barrier_bytes;
  unsigned short* A     = (unsigned short*)(ws + off); off += (size_t)16512 * 512 * 2;
  unsigned short* WT    = (unsigned short*)(ws + off); off += (size_t)4096 * 1536 * 2;
  unsigned short* WPT   = (unsigned short*)(ws + off); off += (size_t)64 * 1024 * 2;
  unsigned short* Zx    = (unsigned short*)(ws + off); off += (size_t)16512 * 4096 * 2;
  unsigned short* hbuf1 = (unsigned short*)(ws + off); off += (size_t)64 * 1024 * 2;
  unsigned short* chainD= (unsigned short*)(ws + off); off += (size_t)256 * 64 * 1024 * 2;
  if (ws_size < off) return;  // insufficient workspace -> loud correctness failure

  hipMemsetAsync(arr, 0, 2 * barrier_bytes, stream);
  hipLaunchKernelGGL(k1a_gather, dim3(16512), dim3(128), 0, stream, tok_src, emb_src, emb_tgt, A);
  hipLaunchKernelGGL(k1w_perm,   dim3(3072),  dim3(256), 0, stream, W_lstm, WT);
  hipLaunchKernelGGL(k1p_perm,   dim3(32),    dim3(256), 0, stream, W_proj, WPT);
  hipLaunchKernelGGL(k2_gemm,    dim3(32, 129), dim3(256), 0, stream, A, WT, Zx);
  hipLaunchKernelGGL(k3_rnn,     dim3(256),   dim3(256), 0, stream, Zx, WT, b_lstm, tok_tgt, hbuf1, chainD, arr, go);
  hipLaunchKernelGGL(k4_proj,    dim3(256),   dim3(256), 0, stream, chainD, WPT, b_proj, out);
}